// Round 2
// baseline (4262.081 us; speedup 1.0000x reference)
//
#include <hip/hip_runtime.h>
#include <math.h>

#define TT 4096
#define BB 2
#define MMDIM 256
#define RTOT 8192
#define NSLICE 39

// ---------------------------------------------------------------------------
// Generic f32 GEMM: C[R][N] = A[R][K] @ W[N][K]^T + bias, optional *sigmoid(gate)
// Tile 64x64, BK=16, 256 threads, 4x4 micro.
// ---------------------------------------------------------------------------
template<int WITH_GATE>
__global__ __launch_bounds__(256) void gemm_f32(
    const float* __restrict__ A, const float* __restrict__ W,
    const float* __restrict__ bias, const float* __restrict__ gate,
    float* __restrict__ C, int K, int N)
{
    __shared__ float As[16][68];
    __shared__ float Ws[16][68];
    const int tid = threadIdx.x;
    const int tx = tid & 15, ty = tid >> 4;
    const int r0 = blockIdx.x * 64, c0 = blockIdx.y * 64;
    const int lr = tid >> 2;          // 0..63
    const int lk = (tid & 3) << 2;    // 0,4,8,12

    float acc[4][4] = {};

    for (int k0 = 0; k0 < K; k0 += 16) {
        float4 av = *(const float4*)&A[(size_t)(r0 + lr) * K + k0 + lk];
        float4 wv = *(const float4*)&W[(size_t)(c0 + lr) * K + k0 + lk];
        As[lk + 0][lr] = av.x; As[lk + 1][lr] = av.y;
        As[lk + 2][lr] = av.z; As[lk + 3][lr] = av.w;
        Ws[lk + 0][lr] = wv.x; Ws[lk + 1][lr] = wv.y;
        Ws[lk + 2][lr] = wv.z; Ws[lk + 3][lr] = wv.w;
        __syncthreads();
        #pragma unroll
        for (int kk = 0; kk < 16; ++kk) {
            float4 a = *(const float4*)&As[kk][ty * 4];
            float4 b = *(const float4*)&Ws[kk][tx * 4];
            acc[0][0] += a.x * b.x; acc[0][1] += a.x * b.y; acc[0][2] += a.x * b.z; acc[0][3] += a.x * b.w;
            acc[1][0] += a.y * b.x; acc[1][1] += a.y * b.y; acc[1][2] += a.y * b.z; acc[1][3] += a.y * b.w;
            acc[2][0] += a.z * b.x; acc[2][1] += a.z * b.y; acc[2][2] += a.z * b.z; acc[2][3] += a.z * b.w;
            acc[3][0] += a.w * b.x; acc[3][1] += a.w * b.y; acc[3][2] += a.w * b.z; acc[3][3] += a.w * b.w;
        }
        __syncthreads();
    }

    float g = 1.f;
    if (WITH_GATE) g = 1.f / (1.f + expf(-gate[0]));
    #pragma unroll
    for (int i = 0; i < 4; ++i) {
        int row = r0 + ty * 4 + i;
        float4 o;
        o.x = (acc[i][0] + bias[c0 + tx * 4 + 0]) * g;
        o.y = (acc[i][1] + bias[c0 + tx * 4 + 1]) * g;
        o.z = (acc[i][2] + bias[c0 + tx * 4 + 2]) * g;
        o.w = (acc[i][3] + bias[c0 + tx * 4 + 3]) * g;
        *(float4*)&C[(size_t)row * N + c0 + tx * 4] = o;
    }
}

// ---------------------------------------------------------------------------
// Pad-copy Ws1 [256][2055] -> [256][2064] (zero pad) so gemm_si can vec4-load.
// ---------------------------------------------------------------------------
__global__ __launch_bounds__(256) void pad_ws1(const float* __restrict__ src,
                                               float* __restrict__ dst)
{
    const int r = blockIdx.x;
    for (int c = threadIdx.x; c < 2064; c += 256)
        dst[(size_t)r * 2064 + c] = (c < 2055) ? src[(size_t)r * 2055 + c] : 0.f;
}

// ---------------------------------------------------------------------------
// h GEMM with fused si = concat(mu, -log(max(lam,1e-6)), pi), vec4 staging.
// K_eff = 2064 (zero-padded); boundaries 1024/2048 are multiples of 16 so each
// 4-float staging quad falls in exactly one segment.
// ---------------------------------------------------------------------------
__global__ __launch_bounds__(256) void gemm_si(
    const float* __restrict__ mu, const float* __restrict__ lam,
    const float* __restrict__ pi, const float* __restrict__ Wp,
    const float* __restrict__ bias, float* __restrict__ C)
{
    __shared__ float As[16][68];
    __shared__ float Ws[16][68];
    const int tid = threadIdx.x;
    const int tx = tid & 15, ty = tid >> 4;
    const int r0 = blockIdx.x * 64, c0 = blockIdx.y * 64;
    const int lr = tid >> 2;
    const int lk = (tid & 3) << 2;

    float acc[4][4] = {};

    for (int k0 = 0; k0 < 2064; k0 += 16) {
        const int kk = k0 + lk;
        float4 av;
        if (kk < 1024) {
            av = *(const float4*)&mu[(size_t)(r0 + lr) * 1024 + kk];
        } else if (kk < 2048) {
            float4 lv = *(const float4*)&lam[(size_t)(r0 + lr) * 1024 + (kk - 1024)];
            av.x = -logf(fmaxf(lv.x, 1e-6f));
            av.y = -logf(fmaxf(lv.y, 1e-6f));
            av.z = -logf(fmaxf(lv.z, 1e-6f));
            av.w = -logf(fmaxf(lv.w, 1e-6f));
        } else {
            #pragma unroll
            for (int i = 0; i < 4; ++i) {
                int k2 = kk + i - 2048;
                ((float*)&av)[i] = (k2 < 7) ? pi[(size_t)(r0 + lr) * 7 + k2] : 0.f;
            }
        }
        float4 wv = *(const float4*)&Wp[(size_t)(c0 + lr) * 2064 + kk];
        As[lk + 0][lr] = av.x; As[lk + 1][lr] = av.y;
        As[lk + 2][lr] = av.z; As[lk + 3][lr] = av.w;
        Ws[lk + 0][lr] = wv.x; Ws[lk + 1][lr] = wv.y;
        Ws[lk + 2][lr] = wv.z; Ws[lk + 3][lr] = wv.w;
        __syncthreads();
        #pragma unroll
        for (int kx = 0; kx < 16; ++kx) {
            float4 a = *(const float4*)&As[kx][ty * 4];
            float4 b = *(const float4*)&Ws[kx][tx * 4];
            acc[0][0] += a.x * b.x; acc[0][1] += a.x * b.y; acc[0][2] += a.x * b.z; acc[0][3] += a.x * b.w;
            acc[1][0] += a.y * b.x; acc[1][1] += a.y * b.y; acc[1][2] += a.y * b.z; acc[1][3] += a.y * b.w;
            acc[2][0] += a.z * b.x; acc[2][1] += a.z * b.y; acc[2][2] += a.z * b.z; acc[2][3] += a.z * b.w;
            acc[3][0] += a.w * b.x; acc[3][1] += a.w * b.y; acc[3][2] += a.w * b.z; acc[3][3] += a.w * b.w;
        }
        __syncthreads();
    }

    #pragma unroll
    for (int i = 0; i < 4; ++i) {
        int row = r0 + ty * 4 + i;
        float4 o;
        o.x = acc[i][0] + bias[c0 + tx * 4 + 0];
        o.y = acc[i][1] + bias[c0 + tx * 4 + 1];
        o.z = acc[i][2] + bias[c0 + tx * 4 + 2];
        o.w = acc[i][3] + bias[c0 + tx * 4 + 3];
        *(float4*)&C[(size_t)row * MMDIM + c0 + tx * 4] = o;
    }
}

// ---------------------------------------------------------------------------
// s gate + kappa' precompute. One wave per token.
// ---------------------------------------------------------------------------
__global__ __launch_bounds__(256) void s_kernel(
    const float* __restrict__ h, const float* __restrict__ Ws2,
    const float* __restrict__ bs2, float* __restrict__ sb,
    float* __restrict__ kap)
{
    const int tid = threadIdx.x;
    const int wave = tid >> 6, lane = tid & 63;
    const int t = blockIdx.x * 4 + wave;

    float4 hv = *(const float4*)&h[(size_t)t * MMDIM + lane * 4];
    float4 wv = *(const float4*)&Ws2[lane * 4];
    float p = 0.f;
    p += (hv.x / (1.f + expf(-hv.x))) * wv.x;
    p += (hv.y / (1.f + expf(-hv.y))) * wv.y;
    p += (hv.z / (1.f + expf(-hv.z))) * wv.z;
    p += (hv.w / (1.f + expf(-hv.w))) * wv.w;
    #pragma unroll
    for (int o = 32; o; o >>= 1) p += __shfl_xor(p, o);

    float z = p + bs2[0];
    float s = 1.f / (1.f + expf(-z));
    float c = s * 12.f;
    float Z = 0.f;
    #pragma unroll
    for (int l = 0; l < 13; ++l) {
        float d = (float)l - c;
        Z += expf(-0.5f * d * d);
    }
    Z = fmaxf(Z, 1e-8f);
    if (lane < 13) {
        float d = (float)lane - c;
        kap[(size_t)t * 16 + lane] = (1.f - s) * expf(-0.5f * d * d) / Z;
    }
    if (lane == 0) sb[t] = s;
}

// ---------------------------------------------------------------------------
// Scratch attention (S=8): ctx[t] = s * softmax(sq.scratch/16) @ scratch
// ---------------------------------------------------------------------------
__global__ __launch_bounds__(256) void scratch_kernel(
    const float* __restrict__ sq, const float* __restrict__ scr,
    const float* __restrict__ sb, float* __restrict__ ctx)
{
    const int tid = threadIdx.x;
    const int wave = tid >> 6, lane = tid & 63;
    const int t = blockIdx.x * 4 + wave;

    float4 qv = *(const float4*)&sq[(size_t)t * MMDIM + lane * 4];
    float4 fr[8];
    float sc[8];
    #pragma unroll
    for (int s = 0; s < 8; ++s) {
        fr[s] = *(const float4*)&scr[s * MMDIM + lane * 4];
        sc[s] = qv.x * fr[s].x + qv.y * fr[s].y + qv.z * fr[s].z + qv.w * fr[s].w;
    }
    #pragma unroll
    for (int s = 0; s < 8; ++s) {
        #pragma unroll
        for (int o = 32; o; o >>= 1) sc[s] += __shfl_xor(sc[s], o);
        sc[s] *= 0.0625f;
    }
    float mx = sc[0];
    #pragma unroll
    for (int s = 1; s < 8; ++s) mx = fmaxf(mx, sc[s]);
    float sum = 0.f;
    #pragma unroll
    for (int s = 0; s < 8; ++s) { sc[s] = expf(sc[s] - mx); sum += sc[s]; }
    float inv = 1.f / sum;
    float blend = sb[t];
    float4 o = {0, 0, 0, 0};
    #pragma unroll
    for (int s = 0; s < 8; ++s) {
        float pp = sc[s] * inv;
        o.x += pp * fr[s].x; o.y += pp * fr[s].y;
        o.z += pp * fr[s].z; o.w += pp * fr[s].w;
    }
    o.x *= blend; o.y *= blend; o.z *= blend; o.w *= blend;
    *(float4*)&ctx[(size_t)t * MMDIM + lane * 4] = o;
}

// ---------------------------------------------------------------------------
// Tree build (levels 1..12).
// ---------------------------------------------------------------------------
__global__ __launch_bounds__(256) void tree_kernel(
    const float* __restrict__ kleaf, const float* __restrict__ vleaf,
    const float* __restrict__ pw, float* __restrict__ ktree,
    float* __restrict__ vtree)
{
    __shared__ float wb[8192];
    const int tid = threadIdx.x;
    const int mc = blockIdx.x;
    const int isv = blockIdx.y;
    const int b = blockIdx.z;

    for (int t = tid; t < 4096; t += 256) wb[t] = pw[b * 4096 + t];
    __syncthreads();
    {
        int src = 0, dst = 4096, n = 4096;
        while (n > 1) {
            int nout = n >> 1;
            for (int j = tid; j < nout; j += 256)
                wb[dst + j] = wb[src + 2 * j] + wb[src + 2 * j + 1] + 1e-8f;
            __syncthreads();
            src = dst; dst += nout; n = nout;
        }
    }

    const float* leaf = isv ? vleaf : kleaf;
    float* tout = isv ? vtree : ktree;
    const int m = mc * 64 + (tid & 63);
    const int j0 = tid >> 6;

    const float* in = leaf + (size_t)b * 4096 * MMDIM;
    int src = 0, dst = 4096, n = 4096, treeoff = 0;
    while (n > 1) {
        int nout = n >> 1;
        float* out = tout + (size_t)(b * 4095 + treeoff) * MMDIM;
        for (int j = j0; j < nout; j += 4) {
            float w1 = wb[src + 2 * j], w2 = wb[src + 2 * j + 1];
            float tw = wb[dst + j];
            float x1 = in[(size_t)(2 * j) * MMDIM + m];
            float x2 = in[(size_t)(2 * j + 1) * MMDIM + m];
            out[(size_t)j * MMDIM + m] = (w1 * x1 + w2 * x2) / tw;
        }
        __syncthreads();
        in = out; src = dst; dst += nout; treeoff += nout; n = nout;
    }
}

// ---------------------------------------------------------------------------
// top-4 helpers (tie-break: lower index, matching jax top_k)
// ---------------------------------------------------------------------------
__device__ __forceinline__ bool beats(float v, int id, float v2, int id2)
{
    return (v > v2) || (v == v2 && id < id2);
}

__device__ __forceinline__ void ins4(float v, int id, float tv[4], int ti[4])
{
    if (!beats(v, id, tv[3], ti[3])) return;
    tv[3] = v; ti[3] = id;
    #pragma unroll
    for (int s = 3; s > 0; --s) {
        if (beats(tv[s], ti[s], tv[s - 1], ti[s - 1])) {
            float fv = tv[s]; tv[s] = tv[s - 1]; tv[s - 1] = fv;
            int iv = ti[s]; ti[s] = ti[s - 1]; ti[s - 1] = iv;
        }
    }
}

// slice id -> (level, col base). 39 slices of <=256 cols.
__device__ __forceinline__ void slice_map(int sid, int& level, int& c0)
{
    if (sid < 16)      { level = 0; c0 = sid << 8; }
    else if (sid < 24) { level = 1; c0 = (sid - 16) << 8; }
    else if (sid < 28) { level = 2; c0 = (sid - 24) << 8; }
    else if (sid < 30) { level = 3; c0 = (sid - 28) << 8; }
    else               { level = sid - 26; c0 = 0; }
}

// ---------------------------------------------------------------------------
// Phase 1: per (64-row group, slice) partial top-4. lane = row; k via
// wave-uniform loads (SMEM path); q staged in LDS [m][row] (stride-1 b32).
// ---------------------------------------------------------------------------
__global__ __launch_bounds__(256) void topk_kernel(
    const float* __restrict__ q, const float* __restrict__ kl0,
    const float* __restrict__ ktree, float2* __restrict__ topw)
{
    __shared__ float qs[256 * 64];       // [m][row]  64 KB
    __shared__ float2 mrg[4][64][4];     // 8 KB

    const int tid = threadIdx.x;
    const int lane = tid & 63;
    const int wv = __builtin_amdgcn_readfirstlane(tid >> 6);
    const int rg = blockIdx.x;           // 0..127
    const int sid = blockIdx.y;          // 0..38
    const int r0 = rg * 64;
    const int b = r0 >> 12;
    const int t0 = r0 & 4095;

    int level, c0b;
    slice_map(sid, level, c0b);
    const int n = TT >> level;
    const int nv = min(min(n, t0 + 64), c0b + 256);

    if (c0b >= nv) {
        if (wv == 0) {
            float2 e = make_float2(-INFINITY, __int_as_float(0x7fffffff));
            #pragma unroll
            for (int s = 0; s < 4; ++s)
                topw[(size_t)(sid * 4 + s) * RTOT + r0 + lane] = e;
        }
        return;
    }

    // stage q [m][row]
    {
        const float* qb = q + (size_t)r0 * MMDIM;
        #pragma unroll
        for (int g = 0; g < 16; ++g) {
            int e = tid + g * 256;       // 0..4095
            int row = e >> 6, qd = e & 63;
            float4 v = *(const float4*)&qb[(size_t)row * MMDIM + qd * 4];
            qs[(qd * 4 + 0) * 64 + row] = v.x;
            qs[(qd * 4 + 1) * 64 + row] = v.y;
            qs[(qd * 4 + 2) * 64 + row] = v.z;
            qs[(qd * 4 + 3) * 64 + row] = v.w;
        }
    }
    __syncthreads();

    const float* Kb = (level == 0)
        ? kl0 + (size_t)b * TT * MMDIM
        : ktree + ((size_t)b * 4095 + (TT - (8192 >> level))) * MMDIM;

    float tv[4]; int ti[4];
    #pragma unroll
    for (int s = 0; s < 4; ++s) { tv[s] = -INFINITY; ti[s] = 0x7fffffff; }
    const int t_lane = t0 + lane;
    const float* qrow = qs + lane;

    for (int tt = wv; tt < 16; tt += 4) {
        const int ct0 = c0b + tt * 16;
        if (ct0 >= nv) continue;                 // uniform within wave
        const int jmax = min(16, n - ct0);
        float acc[16] = {};

        for (int mm4 = 0; mm4 < 64; ++mm4) {
            float q0 = qrow[(mm4 * 4 + 0) * 64];
            float q1 = qrow[(mm4 * 4 + 1) * 64];
            float q2 = qrow[(mm4 * 4 + 2) * 64];
            float q3 = qrow[(mm4 * 4 + 3) * 64];
            #pragma unroll
            for (int j = 0; j < 16; ++j) {
                if (j < jmax) {
                    float4 kv = *(const float4*)&Kb[(size_t)(ct0 + j) * MMDIM + mm4 * 4];
                    acc[j] = fmaf(q0, kv.x, fmaf(q1, kv.y,
                             fmaf(q2, kv.z, fmaf(q3, kv.w, acc[j]))));
                }
            }
        }
        #pragma unroll
        for (int j = 0; j < 16; ++j) {
            if (j < jmax) {
                int c = ct0 + j;
                if (c <= t_lane) ins4(acc[j] * 0.0625f, c, tv, ti);
            }
        }
    }

    #pragma unroll
    for (int s = 0; s < 4; ++s)
        mrg[wv][lane][s] = make_float2(tv[s], __int_as_float(ti[s]));
    __syncthreads();

    if (wv == 0) {
        float fv[4]; int fi[4];
        #pragma unroll
        for (int s = 0; s < 4; ++s) { fv[s] = -INFINITY; fi[s] = 0x7fffffff; }
        #pragma unroll
        for (int w = 0; w < 4; ++w)
            #pragma unroll
            for (int s = 0; s < 4; ++s) {
                float2 e = mrg[w][lane][s];
                ins4(e.x, __float_as_int(e.y), fv, fi);
            }
        #pragma unroll
        for (int s = 0; s < 4; ++s)
            topw[(size_t)(sid * 4 + s) * RTOT + r0 + lane] =
                make_float2(fv[s], __int_as_float(fi[s]));
    }
}

// ---------------------------------------------------------------------------
// Phase 2: per row, per level: merge slice top-4s, softmax, kappa-weighted V
// gather; combine with s*scratch_ctx already in ctx. One wave per row.
// ---------------------------------------------------------------------------
__global__ __launch_bounds__(256) void merge_gather(
    const float2* __restrict__ topw, const float* __restrict__ vl0,
    const float* __restrict__ vtree, const float* __restrict__ kap,
    float* __restrict__ ctx)
{
    const int tid = threadIdx.x;
    const int lane = tid & 63;
    const int wv = __builtin_amdgcn_readfirstlane(tid >> 6);
    const int row = blockIdx.x * 4 + wv;     // 0..8191
    const int b = row >> 12;

    float cr[4] = {0, 0, 0, 0};

    for (int l = 0; l <= 12; ++l) {
        int s0, cnt;
        if (l == 0)      { s0 = 0;  cnt = 16; }
        else if (l == 1) { s0 = 16; cnt = 8; }
        else if (l == 2) { s0 = 24; cnt = 4; }
        else if (l == 3) { s0 = 28; cnt = 2; }
        else             { s0 = 26 + l; cnt = 1; }

        float tv[4]; int ti[4];
        #pragma unroll
        for (int s = 0; s < 4; ++s) { tv[s] = -INFINITY; ti[s] = 0x7fffffff; }
        for (int sl = 0; sl < cnt; ++sl) {
            #pragma unroll
            for (int s = 0; s < 4; ++s) {
                float2 e = topw[(size_t)((s0 + sl) * 4 + s) * RTOT + row];
                if (e.x > -INFINITY) ins4(e.x, __float_as_int(e.y), tv, ti);
            }
        }

        float m0 = tv[0];
        float e0 = expf(tv[0] - m0);
        float e1 = expf(tv[1] - m0);
        float e2 = expf(tv[2] - m0);
        float e3 = expf(tv[3] - m0);
        float sum = e0 + e1 + e2 + e3;
        float kp = kap[(size_t)row * 16 + l];
        float scl = kp / sum;
        float ps[4] = {e0 * scl, e1 * scl, e2 * scl, e3 * scl};

        const float* Vb = (l == 0)
            ? vl0 + (size_t)b * TT * MMDIM
            : vtree + ((size_t)b * 4095 + (TT - (8192 >> l))) * MMDIM;

        #pragma unroll
        for (int s = 0; s < 4; ++s) {
            if (ps[s] > 0.f) {
                float4 vv = *(const float4*)&Vb[(size_t)ti[s] * MMDIM + lane * 4];
                cr[0] += ps[s] * vv.x; cr[1] += ps[s] * vv.y;
                cr[2] += ps[s] * vv.z; cr[3] += ps[s] * vv.w;
            }
        }
    }

    float* cp = ctx + (size_t)row * MMDIM + lane * 4;
    float4 c = *(float4*)cp;
    c.x += cr[0]; c.y += cr[1]; c.z += cr[2]; c.w += cr[3];
    *(float4*)cp = c;
}

// ---------------------------------------------------------------------------
extern "C" void kernel_launch(void* const* d_in, const int* in_sizes, int n_in,
                              void* d_out, int out_size, void* d_ws, size_t ws_size,
                              hipStream_t stream)
{
    const float* mu  = (const float*)d_in[0];
    const float* lam = (const float*)d_in[1];
    const float* pi  = (const float*)d_in[2];
    const float* pw  = (const float*)d_in[3];
    const float* Wq  = (const float*)d_in[4];
    const float* bq  = (const float*)d_in[5];
    const float* Wk  = (const float*)d_in[6];
    const float* bk  = (const float*)d_in[7];
    const float* Wv  = (const float*)d_in[8];
    const float* bv  = (const float*)d_in[9];
    const float* Wo  = (const float*)d_in[10];
    const float* bo  = (const float*)d_in[11];
    const float* Ws1 = (const float*)d_in[12];
    const float* bs1 = (const float*)d_in[13];
    const float* Ws2 = (const float*)d_in[14];
    const float* bs2 = (const float*)d_in[15];
    const float* Wsr = (const float*)d_in[16];
    const float* bsr = (const float*)d_in[17];
    const float* scr = (const float*)d_in[18];
    const float* gate = (const float*)d_in[19];
    float* out = (float*)d_out;

    float* w = (float*)d_ws;
    const size_t RM = (size_t)RTOT * MMDIM;
    float* q_   = w;  w += RM;
    float* k_   = w;  w += RM;
    float* v_   = w;  w += RM;
    float* h_   = w;  w += RM;
    float* sq_  = w;  w += RM;
    float* ctx_ = w;  w += RM;
    float* sb_  = w;  w += RTOT;
    float* kap_ = w;  w += (size_t)RTOT * 16;
    float* kt_  = w;  w += (size_t)BB * 4095 * MMDIM;
    float* vt_  = w;  w += (size_t)BB * 4095 * MMDIM;
    float* w1p_ = w;  w += (size_t)256 * 2064;
    float2* topw = (float2*)w;  w += (size_t)NSLICE * 4 * RTOT * 2;

    gemm_f32<0><<<dim3(128, 4), 256, 0, stream>>>(mu, Wq, bq, nullptr, q_, 1024, 256);
    gemm_f32<0><<<dim3(128, 4), 256, 0, stream>>>(mu, Wk, bk, nullptr, k_, 1024, 256);
    gemm_f32<0><<<dim3(128, 4), 256, 0, stream>>>(mu, Wv, bv, nullptr, v_, 1024, 256);
    pad_ws1<<<256, 256, 0, stream>>>(Ws1, w1p_);
    gemm_si<<<dim3(128, 4), 256, 0, stream>>>(mu, lam, pi, w1p_, bs1, h_);
    s_kernel<<<2048, 256, 0, stream>>>(h_, Ws2, bs2, sb_, kap_);
    gemm_f32<0><<<dim3(128, 4), 256, 0, stream>>>(q_, Wsr, bsr, nullptr, sq_, 256, 256);
    scratch_kernel<<<2048, 256, 0, stream>>>(sq_, scr, sb_, ctx_);
    tree_kernel<<<dim3(4, 2, 2), 256, 0, stream>>>(k_, v_, pw, kt_, vt_);
    topk_kernel<<<dim3(128, NSLICE), 256, 0, stream>>>(q_, k_, kt_, topw);
    merge_gather<<<2048, 256, 0, stream>>>(topw, v_, vt_, kap_, ctx_);
    gemm_f32<1><<<dim3(128, 16), 256, 0, stream>>>(ctx_, Wo, bo, gate, out, 256, 1024);
}

// Round 3
// 1597.853 us; speedup vs baseline: 2.6674x; 2.6674x over previous
//
#include <hip/hip_runtime.h>
#include <math.h>

#define TT 4096
#define BB 2
#define MMDIM 256
#define RTOT 8192
#define NSLICE 39

// ---------------------------------------------------------------------------
// Generic f32 GEMM: C[R][N] = A[R][K] @ W[N][K]^T + bias, optional *sigmoid(gate)
// Tile 64x64, BK=16, 256 threads, 4x4 micro.
// ---------------------------------------------------------------------------
template<int WITH_GATE>
__global__ __launch_bounds__(256) void gemm_f32(
    const float* __restrict__ A, const float* __restrict__ W,
    const float* __restrict__ bias, const float* __restrict__ gate,
    float* __restrict__ C, int K, int N)
{
    __shared__ float As[16][68];
    __shared__ float Ws[16][68];
    const int tid = threadIdx.x;
    const int tx = tid & 15, ty = tid >> 4;
    const int r0 = blockIdx.x * 64, c0 = blockIdx.y * 64;
    const int lr = tid >> 2;          // 0..63
    const int lk = (tid & 3) << 2;    // 0,4,8,12

    float acc[4][4] = {};

    for (int k0 = 0; k0 < K; k0 += 16) {
        float4 av = *(const float4*)&A[(size_t)(r0 + lr) * K + k0 + lk];
        float4 wv = *(const float4*)&W[(size_t)(c0 + lr) * K + k0 + lk];
        As[lk + 0][lr] = av.x; As[lk + 1][lr] = av.y;
        As[lk + 2][lr] = av.z; As[lk + 3][lr] = av.w;
        Ws[lk + 0][lr] = wv.x; Ws[lk + 1][lr] = wv.y;
        Ws[lk + 2][lr] = wv.z; Ws[lk + 3][lr] = wv.w;
        __syncthreads();
        #pragma unroll
        for (int kk = 0; kk < 16; ++kk) {
            float4 a = *(const float4*)&As[kk][ty * 4];
            float4 b = *(const float4*)&Ws[kk][tx * 4];
            acc[0][0] += a.x * b.x; acc[0][1] += a.x * b.y; acc[0][2] += a.x * b.z; acc[0][3] += a.x * b.w;
            acc[1][0] += a.y * b.x; acc[1][1] += a.y * b.y; acc[1][2] += a.y * b.z; acc[1][3] += a.y * b.w;
            acc[2][0] += a.z * b.x; acc[2][1] += a.z * b.y; acc[2][2] += a.z * b.z; acc[2][3] += a.z * b.w;
            acc[3][0] += a.w * b.x; acc[3][1] += a.w * b.y; acc[3][2] += a.w * b.z; acc[3][3] += a.w * b.w;
        }
        __syncthreads();
    }

    float g = 1.f;
    if (WITH_GATE) g = 1.f / (1.f + expf(-gate[0]));
    #pragma unroll
    for (int i = 0; i < 4; ++i) {
        int row = r0 + ty * 4 + i;
        float4 o;
        o.x = (acc[i][0] + bias[c0 + tx * 4 + 0]) * g;
        o.y = (acc[i][1] + bias[c0 + tx * 4 + 1]) * g;
        o.z = (acc[i][2] + bias[c0 + tx * 4 + 2]) * g;
        o.w = (acc[i][3] + bias[c0 + tx * 4 + 3]) * g;
        *(float4*)&C[(size_t)row * N + c0 + tx * 4] = o;
    }
}

// ---------------------------------------------------------------------------
// Pad-copy Ws1 [256][2055] -> [256][2064] (zero pad) so gemm_si can vec4-load.
// ---------------------------------------------------------------------------
__global__ __launch_bounds__(256) void pad_ws1(const float* __restrict__ src,
                                               float* __restrict__ dst)
{
    const int r = blockIdx.x;
    for (int c = threadIdx.x; c < 2064; c += 256)
        dst[(size_t)r * 2064 + c] = (c < 2055) ? src[(size_t)r * 2055 + c] : 0.f;
}

// ---------------------------------------------------------------------------
// h GEMM with fused si = concat(mu, -log(max(lam,1e-6)), pi), vec4 staging.
// ---------------------------------------------------------------------------
__global__ __launch_bounds__(256) void gemm_si(
    const float* __restrict__ mu, const float* __restrict__ lam,
    const float* __restrict__ pi, const float* __restrict__ Wp,
    const float* __restrict__ bias, float* __restrict__ C)
{
    __shared__ float As[16][68];
    __shared__ float Ws[16][68];
    const int tid = threadIdx.x;
    const int tx = tid & 15, ty = tid >> 4;
    const int r0 = blockIdx.x * 64, c0 = blockIdx.y * 64;
    const int lr = tid >> 2;
    const int lk = (tid & 3) << 2;

    float acc[4][4] = {};

    for (int k0 = 0; k0 < 2064; k0 += 16) {
        const int kk = k0 + lk;
        float4 av;
        if (kk < 1024) {
            av = *(const float4*)&mu[(size_t)(r0 + lr) * 1024 + kk];
        } else if (kk < 2048) {
            float4 lv = *(const float4*)&lam[(size_t)(r0 + lr) * 1024 + (kk - 1024)];
            av.x = -logf(fmaxf(lv.x, 1e-6f));
            av.y = -logf(fmaxf(lv.y, 1e-6f));
            av.z = -logf(fmaxf(lv.z, 1e-6f));
            av.w = -logf(fmaxf(lv.w, 1e-6f));
        } else {
            #pragma unroll
            for (int i = 0; i < 4; ++i) {
                int k2 = kk + i - 2048;
                ((float*)&av)[i] = (k2 < 7) ? pi[(size_t)(r0 + lr) * 7 + k2] : 0.f;
            }
        }
        float4 wv = *(const float4*)&Wp[(size_t)(c0 + lr) * 2064 + kk];
        As[lk + 0][lr] = av.x; As[lk + 1][lr] = av.y;
        As[lk + 2][lr] = av.z; As[lk + 3][lr] = av.w;
        Ws[lk + 0][lr] = wv.x; Ws[lk + 1][lr] = wv.y;
        Ws[lk + 2][lr] = wv.z; Ws[lk + 3][lr] = wv.w;
        __syncthreads();
        #pragma unroll
        for (int kx = 0; kx < 16; ++kx) {
            float4 a = *(const float4*)&As[kx][ty * 4];
            float4 b = *(const float4*)&Ws[kx][tx * 4];
            acc[0][0] += a.x * b.x; acc[0][1] += a.x * b.y; acc[0][2] += a.x * b.z; acc[0][3] += a.x * b.w;
            acc[1][0] += a.y * b.x; acc[1][1] += a.y * b.y; acc[1][2] += a.y * b.z; acc[1][3] += a.y * b.w;
            acc[2][0] += a.z * b.x; acc[2][1] += a.z * b.y; acc[2][2] += a.z * b.z; acc[2][3] += a.z * b.w;
            acc[3][0] += a.w * b.x; acc[3][1] += a.w * b.y; acc[3][2] += a.w * b.z; acc[3][3] += a.w * b.w;
        }
        __syncthreads();
    }

    #pragma unroll
    for (int i = 0; i < 4; ++i) {
        int row = r0 + ty * 4 + i;
        float4 o;
        o.x = acc[i][0] + bias[c0 + tx * 4 + 0];
        o.y = acc[i][1] + bias[c0 + tx * 4 + 1];
        o.z = acc[i][2] + bias[c0 + tx * 4 + 2];
        o.w = acc[i][3] + bias[c0 + tx * 4 + 3];
        *(float4*)&C[(size_t)row * MMDIM + c0 + tx * 4] = o;
    }
}

// ---------------------------------------------------------------------------
// s gate + kappa' precompute. One wave per token.
// ---------------------------------------------------------------------------
__global__ __launch_bounds__(256) void s_kernel(
    const float* __restrict__ h, const float* __restrict__ Ws2,
    const float* __restrict__ bs2, float* __restrict__ sb,
    float* __restrict__ kap)
{
    const int tid = threadIdx.x;
    const int wave = tid >> 6, lane = tid & 63;
    const int t = blockIdx.x * 4 + wave;

    float4 hv = *(const float4*)&h[(size_t)t * MMDIM + lane * 4];
    float4 wv = *(const float4*)&Ws2[lane * 4];
    float p = 0.f;
    p += (hv.x / (1.f + expf(-hv.x))) * wv.x;
    p += (hv.y / (1.f + expf(-hv.y))) * wv.y;
    p += (hv.z / (1.f + expf(-hv.z))) * wv.z;
    p += (hv.w / (1.f + expf(-hv.w))) * wv.w;
    #pragma unroll
    for (int o = 32; o; o >>= 1) p += __shfl_xor(p, o);

    float z = p + bs2[0];
    float s = 1.f / (1.f + expf(-z));
    float c = s * 12.f;
    float Z = 0.f;
    #pragma unroll
    for (int l = 0; l < 13; ++l) {
        float d = (float)l - c;
        Z += expf(-0.5f * d * d);
    }
    Z = fmaxf(Z, 1e-8f);
    if (lane < 13) {
        float d = (float)lane - c;
        kap[(size_t)t * 16 + lane] = (1.f - s) * expf(-0.5f * d * d) / Z;
    }
    if (lane == 0) sb[t] = s;
}

// ---------------------------------------------------------------------------
// Scratch attention (S=8): ctx[t] = s * softmax(sq.scratch/16) @ scratch
// ---------------------------------------------------------------------------
__global__ __launch_bounds__(256) void scratch_kernel(
    const float* __restrict__ sq, const float* __restrict__ scr,
    const float* __restrict__ sb, float* __restrict__ ctx)
{
    const int tid = threadIdx.x;
    const int wave = tid >> 6, lane = tid & 63;
    const int t = blockIdx.x * 4 + wave;

    float4 qv = *(const float4*)&sq[(size_t)t * MMDIM + lane * 4];
    float4 fr[8];
    float sc[8];
    #pragma unroll
    for (int s = 0; s < 8; ++s) {
        fr[s] = *(const float4*)&scr[s * MMDIM + lane * 4];
        sc[s] = qv.x * fr[s].x + qv.y * fr[s].y + qv.z * fr[s].z + qv.w * fr[s].w;
    }
    #pragma unroll
    for (int s = 0; s < 8; ++s) {
        #pragma unroll
        for (int o = 32; o; o >>= 1) sc[s] += __shfl_xor(sc[s], o);
        sc[s] *= 0.0625f;
    }
    float mx = sc[0];
    #pragma unroll
    for (int s = 1; s < 8; ++s) mx = fmaxf(mx, sc[s]);
    float sum = 0.f;
    #pragma unroll
    for (int s = 0; s < 8; ++s) { sc[s] = expf(sc[s] - mx); sum += sc[s]; }
    float inv = 1.f / sum;
    float blend = sb[t];
    float4 o = {0, 0, 0, 0};
    #pragma unroll
    for (int s = 0; s < 8; ++s) {
        float pp = sc[s] * inv;
        o.x += pp * fr[s].x; o.y += pp * fr[s].y;
        o.z += pp * fr[s].z; o.w += pp * fr[s].w;
    }
    o.x *= blend; o.y *= blend; o.z *= blend; o.w *= blend;
    *(float4*)&ctx[(size_t)t * MMDIM + lane * 4] = o;
}

// ---------------------------------------------------------------------------
// Tree build (levels 1..12).
// ---------------------------------------------------------------------------
__global__ __launch_bounds__(256) void tree_kernel(
    const float* __restrict__ kleaf, const float* __restrict__ vleaf,
    const float* __restrict__ pw, float* __restrict__ ktree,
    float* __restrict__ vtree)
{
    __shared__ float wb[8192];
    const int tid = threadIdx.x;
    const int mc = blockIdx.x;
    const int isv = blockIdx.y;
    const int b = blockIdx.z;

    for (int t = tid; t < 4096; t += 256) wb[t] = pw[b * 4096 + t];
    __syncthreads();
    {
        int src = 0, dst = 4096, n = 4096;
        while (n > 1) {
            int nout = n >> 1;
            for (int j = tid; j < nout; j += 256)
                wb[dst + j] = wb[src + 2 * j] + wb[src + 2 * j + 1] + 1e-8f;
            __syncthreads();
            src = dst; dst += nout; n = nout;
        }
    }

    const float* leaf = isv ? vleaf : kleaf;
    float* tout = isv ? vtree : ktree;
    const int m = mc * 64 + (tid & 63);
    const int j0 = tid >> 6;

    const float* in = leaf + (size_t)b * 4096 * MMDIM;
    int src = 0, dst = 4096, n = 4096, treeoff = 0;
    while (n > 1) {
        int nout = n >> 1;
        float* out = tout + (size_t)(b * 4095 + treeoff) * MMDIM;
        for (int j = j0; j < nout; j += 4) {
            float w1 = wb[src + 2 * j], w2 = wb[src + 2 * j + 1];
            float tw = wb[dst + j];
            float x1 = in[(size_t)(2 * j) * MMDIM + m];
            float x2 = in[(size_t)(2 * j + 1) * MMDIM + m];
            out[(size_t)j * MMDIM + m] = (w1 * x1 + w2 * x2) / tw;
        }
        __syncthreads();
        in = out; src = dst; dst += nout; treeoff += nout; n = nout;
    }
}

// ---------------------------------------------------------------------------
// top-4 helpers (tie-break: lower index, matching jax top_k)
// ---------------------------------------------------------------------------
__device__ __forceinline__ bool beats(float v, int id, float v2, int id2)
{
    return (v > v2) || (v == v2 && id < id2);
}

__device__ __forceinline__ void ins4(float v, int id, float tv[4], int ti[4])
{
    if (!beats(v, id, tv[3], ti[3])) return;
    tv[3] = v; ti[3] = id;
    #pragma unroll
    for (int s = 3; s > 0; --s) {
        if (beats(tv[s], ti[s], tv[s - 1], ti[s - 1])) {
            float fv = tv[s]; tv[s] = tv[s - 1]; tv[s - 1] = fv;
            int iv = ti[s]; ti[s] = ti[s - 1]; ti[s - 1] = iv;
        }
    }
}

// slice id -> (level, col base). 39 slices of <=256 cols.
__device__ __forceinline__ void slice_map(int sid, int& level, int& c0)
{
    if (sid < 16)      { level = 0; c0 = sid << 8; }
    else if (sid < 24) { level = 1; c0 = (sid - 16) << 8; }
    else if (sid < 28) { level = 2; c0 = (sid - 24) << 8; }
    else if (sid < 30) { level = 3; c0 = (sid - 28) << 8; }
    else               { level = sid - 26; c0 = 0; }
}

// ---------------------------------------------------------------------------
// Phase 1 (v3): per (32-row group, slice) partial top-4 using the R1 LDS
// micro-tile GEMM (4x4 outer product). 256 threads: tx=col-group(32), ty=
// row-group(8). Two 128-col chunks per slice. Partial top-4 -> topw.
// ---------------------------------------------------------------------------
__global__ __launch_bounds__(256) void topk_kernel(
    const float* __restrict__ q, const float* __restrict__ kl0,
    const float* __restrict__ ktree, float2* __restrict__ topw)
{
    __shared__ float qs[256][36];    // [m][row32]
    __shared__ float ks[64][132];    // [m64][col128]

    const int tid = threadIdx.x;
    const int tx = tid & 31;
    const int ty = tid >> 5;
    const int rg = blockIdx.x;       // 0..255 (32-row groups, both batches)
    const int sid = blockIdx.y;      // 0..38
    const int r0 = rg * 32;
    const int b = r0 >> 12;
    const int t0 = r0 & 4095;

    int level, c0b;
    slice_map(sid, level, c0b);
    const int n = TT >> level;
    const int nv = min(min(n, t0 + 32), c0b + 256);

    if (c0b >= nv) {
        if (tid < 32) {
            float2 e = make_float2(-INFINITY, __int_as_float(0x7fffffff));
            #pragma unroll
            for (int s = 0; s < 4; ++s)
                topw[(size_t)(sid * 4 + s) * RTOT + r0 + tid] = e;
        }
        return;
    }

    // stage q transposed: qs[m][row]
    #pragma unroll
    for (int g = 0; g < 8; ++g) {
        int e = tid + g * 256;        // 0..2047
        int row = e >> 6;
        int qd = e & 63;
        float4 qv = *(const float4*)&q[(size_t)(r0 + row) * MMDIM + qd * 4];
        qs[qd * 4 + 0][row] = qv.x; qs[qd * 4 + 1][row] = qv.y;
        qs[qd * 4 + 2][row] = qv.z; qs[qd * 4 + 3][row] = qv.w;
    }
    __syncthreads();

    const float* Kb = (level == 0)
        ? kl0 + (size_t)b * TT * MMDIM
        : ktree + ((size_t)b * 4095 + (TT - (8192 >> level))) * MMDIM;

    float tv[4][4];
    int ti[4][4];
    #pragma unroll
    for (int i = 0; i < 4; ++i)
        #pragma unroll
        for (int s = 0; s < 4; ++s) { tv[i][s] = -INFINITY; ti[i][s] = 0x7fffffff; }

    for (int c0 = c0b; c0 < nv; c0 += 128) {
        float acc[4][4] = {};
        for (int mc = 0; mc < 4; ++mc) {
            #pragma unroll
            for (int g = 0; g < 8; ++g) {
                int e = tid + g * 256;       // 0..2047
                int col = e >> 4;            // 0..127
                int qd = e & 15;
                float4 kv = {0, 0, 0, 0};
                if (c0 + col < n)
                    kv = *(const float4*)&Kb[(size_t)(c0 + col) * MMDIM + mc * 64 + qd * 4];
                ks[qd * 4 + 0][col] = kv.x; ks[qd * 4 + 1][col] = kv.y;
                ks[qd * 4 + 2][col] = kv.z; ks[qd * 4 + 3][col] = kv.w;
            }
            __syncthreads();
            #pragma unroll 16
            for (int mm = 0; mm < 64; ++mm) {
                float4 a = *(const float4*)&qs[mc * 64 + mm][ty * 4];
                float4 bb = *(const float4*)&ks[mm][tx * 4];
                acc[0][0] += a.x * bb.x; acc[0][1] += a.x * bb.y; acc[0][2] += a.x * bb.z; acc[0][3] += a.x * bb.w;
                acc[1][0] += a.y * bb.x; acc[1][1] += a.y * bb.y; acc[1][2] += a.y * bb.z; acc[1][3] += a.y * bb.w;
                acc[2][0] += a.z * bb.x; acc[2][1] += a.z * bb.y; acc[2][2] += a.z * bb.z; acc[2][3] += a.z * bb.w;
                acc[3][0] += a.w * bb.x; acc[3][1] += a.w * bb.y; acc[3][2] += a.w * bb.z; acc[3][3] += a.w * bb.w;
            }
            __syncthreads();
        }
        // insert candidates (mask: col <= t_row, col < n)
        #pragma unroll
        for (int i = 0; i < 4; ++i) {
            int trow = t0 + ty * 4 + i;
            #pragma unroll
            for (int j = 0; j < 4; ++j) {
                int c = c0 + tx * 4 + j;
                float v = (c < n && c <= trow) ? acc[i][j] * 0.0625f : -INFINITY;
                ins4(v, c, tv[i], ti[i]);
            }
        }
    }

    // butterfly merge of top-4 across the 32 tx lanes
    #pragma unroll
    for (int off = 1; off < 32; off <<= 1) {
        #pragma unroll
        for (int i = 0; i < 4; ++i) {
            float ov[4]; int oi[4];
            #pragma unroll
            for (int s = 0; s < 4; ++s) {
                ov[s] = __shfl_xor(tv[i][s], off);
                oi[s] = __shfl_xor(ti[i][s], off);
            }
            #pragma unroll
            for (int s = 0; s < 4; ++s) ins4(ov[s], oi[s], tv[i], ti[i]);
        }
    }

    if (tx == 0) {
        #pragma unroll
        for (int i = 0; i < 4; ++i)
            #pragma unroll
            for (int s = 0; s < 4; ++s)
                topw[(size_t)(sid * 4 + s) * RTOT + r0 + ty * 4 + i] =
                    make_float2(tv[i][s], __int_as_float(ti[i][s]));
    }
}

// ---------------------------------------------------------------------------
// Phase 2: per row, per level: merge slice top-4s, softmax, kappa-weighted V
// gather; combine with s*scratch_ctx already in ctx. One wave per row.
// ---------------------------------------------------------------------------
__global__ __launch_bounds__(256) void merge_gather(
    const float2* __restrict__ topw, const float* __restrict__ vl0,
    const float* __restrict__ vtree, const float* __restrict__ kap,
    float* __restrict__ ctx)
{
    const int tid = threadIdx.x;
    const int lane = tid & 63;
    const int wv = __builtin_amdgcn_readfirstlane(tid >> 6);
    const int row = blockIdx.x * 4 + wv;     // 0..8191
    const int b = row >> 12;

    float cr[4] = {0, 0, 0, 0};

    for (int l = 0; l <= 12; ++l) {
        int s0, cnt;
        if (l == 0)      { s0 = 0;  cnt = 16; }
        else if (l == 1) { s0 = 16; cnt = 8; }
        else if (l == 2) { s0 = 24; cnt = 4; }
        else if (l == 3) { s0 = 28; cnt = 2; }
        else             { s0 = 26 + l; cnt = 1; }

        float tv[4]; int ti[4];
        #pragma unroll
        for (int s = 0; s < 4; ++s) { tv[s] = -INFINITY; ti[s] = 0x7fffffff; }
        for (int sl = 0; sl < cnt; ++sl) {
            #pragma unroll
            for (int s = 0; s < 4; ++s) {
                float2 e = topw[(size_t)((s0 + sl) * 4 + s) * RTOT + row];
                if (e.x > -INFINITY) ins4(e.x, __float_as_int(e.y), tv, ti);
            }
        }

        float m0 = tv[0];
        float e0 = expf(tv[0] - m0);
        float e1 = expf(tv[1] - m0);
        float e2 = expf(tv[2] - m0);
        float e3 = expf(tv[3] - m0);
        float sum = e0 + e1 + e2 + e3;
        float kp = kap[(size_t)row * 16 + l];
        float scl = kp / sum;
        float ps[4] = {e0 * scl, e1 * scl, e2 * scl, e3 * scl};

        const float* Vb = (l == 0)
            ? vl0 + (size_t)b * TT * MMDIM
            : vtree + ((size_t)b * 4095 + (TT - (8192 >> l))) * MMDIM;

        #pragma unroll
        for (int s = 0; s < 4; ++s) {
            if (ps[s] > 0.f) {
                float4 vv = *(const float4*)&Vb[(size_t)ti[s] * MMDIM + lane * 4];
                cr[0] += ps[s] * vv.x; cr[1] += ps[s] * vv.y;
                cr[2] += ps[s] * vv.z; cr[3] += ps[s] * vv.w;
            }
        }
    }

    float* cp = ctx + (size_t)row * MMDIM + lane * 4;
    float4 c = *(float4*)cp;
    c.x += cr[0]; c.y += cr[1]; c.z += cr[2]; c.w += cr[3];
    *(float4*)cp = c;
}

// ---------------------------------------------------------------------------
extern "C" void kernel_launch(void* const* d_in, const int* in_sizes, int n_in,
                              void* d_out, int out_size, void* d_ws, size_t ws_size,
                              hipStream_t stream)
{
    const float* mu  = (const float*)d_in[0];
    const float* lam = (const float*)d_in[1];
    const float* pi  = (const float*)d_in[2];
    const float* pw  = (const float*)d_in[3];
    const float* Wq  = (const float*)d_in[4];
    const float* bq  = (const float*)d_in[5];
    const float* Wk  = (const float*)d_in[6];
    const float* bk  = (const float*)d_in[7];
    const float* Wv  = (const float*)d_in[8];
    const float* bv  = (const float*)d_in[9];
    const float* Wo  = (const float*)d_in[10];
    const float* bo  = (const float*)d_in[11];
    const float* Ws1 = (const float*)d_in[12];
    const float* bs1 = (const float*)d_in[13];
    const float* Ws2 = (const float*)d_in[14];
    const float* bs2 = (const float*)d_in[15];
    const float* Wsr = (const float*)d_in[16];
    const float* bsr = (const float*)d_in[17];
    const float* scr = (const float*)d_in[18];
    const float* gate = (const float*)d_in[19];
    float* out = (float*)d_out;

    float* w = (float*)d_ws;
    const size_t RM = (size_t)RTOT * MMDIM;
    float* q_   = w;  w += RM;
    float* k_   = w;  w += RM;
    float* v_   = w;  w += RM;
    float* h_   = w;  w += RM;
    float* sq_  = w;  w += RM;
    float* ctx_ = w;  w += RM;
    float* sb_  = w;  w += RTOT;
    float* kap_ = w;  w += (size_t)RTOT * 16;
    float* kt_  = w;  w += (size_t)BB * 4095 * MMDIM;
    float* vt_  = w;  w += (size_t)BB * 4095 * MMDIM;
    float* w1p_ = w;  w += (size_t)256 * 2064;
    float2* topw = (float2*)w;  w += (size_t)NSLICE * 4 * RTOT * 2;

    gemm_f32<0><<<dim3(128, 4), 256, 0, stream>>>(mu, Wq, bq, nullptr, q_, 1024, 256);
    gemm_f32<0><<<dim3(128, 4), 256, 0, stream>>>(mu, Wk, bk, nullptr, k_, 1024, 256);
    gemm_f32<0><<<dim3(128, 4), 256, 0, stream>>>(mu, Wv, bv, nullptr, v_, 1024, 256);
    pad_ws1<<<256, 256, 0, stream>>>(Ws1, w1p_);
    gemm_si<<<dim3(128, 4), 256, 0, stream>>>(mu, lam, pi, w1p_, bs1, h_);
    s_kernel<<<2048, 256, 0, stream>>>(h_, Ws2, bs2, sb_, kap_);
    gemm_f32<0><<<dim3(128, 4), 256, 0, stream>>>(q_, Wsr, bsr, nullptr, sq_, 256, 256);
    scratch_kernel<<<2048, 256, 0, stream>>>(sq_, scr, sb_, ctx_);
    tree_kernel<<<dim3(4, 2, 2), 256, 0, stream>>>(k_, v_, pw, kt_, vt_);
    topk_kernel<<<dim3(256, NSLICE), 256, 0, stream>>>(q_, k_, kt_, topw);
    merge_gather<<<2048, 256, 0, stream>>>(topw, v_, vt_, kap_, ctx_);
    gemm_f32<1><<<dim3(128, 16), 256, 0, stream>>>(ctx_, Wo, bo, gate, out, 256, 1024);
}

// Round 4
// 960.823 us; speedup vs baseline: 4.4359x; 1.6630x over previous
//
#include <hip/hip_runtime.h>
#include <math.h>

#define TT 4096
#define BB 2
#define MMDIM 256
#define RTOT 8192
#define NSLICE 39

typedef __attribute__((ext_vector_type(8))) short short8_t;
typedef __attribute__((ext_vector_type(4))) float f32x4;

// ---------------------------------------------------------------------------
// Generic f32 GEMM: C[R][N] = A[R][K] @ W[N][K]^T + bias, optional *sigmoid(gate)
// ---------------------------------------------------------------------------
template<int WITH_GATE>
__global__ __launch_bounds__(256) void gemm_f32(
    const float* __restrict__ A, const float* __restrict__ W,
    const float* __restrict__ bias, const float* __restrict__ gate,
    float* __restrict__ C, int K, int N)
{
    __shared__ float As[16][68];
    __shared__ float Ws[16][68];
    const int tid = threadIdx.x;
    const int tx = tid & 15, ty = tid >> 4;
    const int r0 = blockIdx.x * 64, c0 = blockIdx.y * 64;
    const int lr = tid >> 2;
    const int lk = (tid & 3) << 2;

    float acc[4][4] = {};

    for (int k0 = 0; k0 < K; k0 += 16) {
        float4 av = *(const float4*)&A[(size_t)(r0 + lr) * K + k0 + lk];
        float4 wv = *(const float4*)&W[(size_t)(c0 + lr) * K + k0 + lk];
        As[lk + 0][lr] = av.x; As[lk + 1][lr] = av.y;
        As[lk + 2][lr] = av.z; As[lk + 3][lr] = av.w;
        Ws[lk + 0][lr] = wv.x; Ws[lk + 1][lr] = wv.y;
        Ws[lk + 2][lr] = wv.z; Ws[lk + 3][lr] = wv.w;
        __syncthreads();
        #pragma unroll
        for (int kk = 0; kk < 16; ++kk) {
            float4 a = *(const float4*)&As[kk][ty * 4];
            float4 b = *(const float4*)&Ws[kk][tx * 4];
            acc[0][0] += a.x * b.x; acc[0][1] += a.x * b.y; acc[0][2] += a.x * b.z; acc[0][3] += a.x * b.w;
            acc[1][0] += a.y * b.x; acc[1][1] += a.y * b.y; acc[1][2] += a.y * b.z; acc[1][3] += a.y * b.w;
            acc[2][0] += a.z * b.x; acc[2][1] += a.z * b.y; acc[2][2] += a.z * b.z; acc[2][3] += a.z * b.w;
            acc[3][0] += a.w * b.x; acc[3][1] += a.w * b.y; acc[3][2] += a.w * b.z; acc[3][3] += a.w * b.w;
        }
        __syncthreads();
    }

    float g = 1.f;
    if (WITH_GATE) g = 1.f / (1.f + expf(-gate[0]));
    #pragma unroll
    for (int i = 0; i < 4; ++i) {
        int row = r0 + ty * 4 + i;
        float4 o;
        o.x = (acc[i][0] + bias[c0 + tx * 4 + 0]) * g;
        o.y = (acc[i][1] + bias[c0 + tx * 4 + 1]) * g;
        o.z = (acc[i][2] + bias[c0 + tx * 4 + 2]) * g;
        o.w = (acc[i][3] + bias[c0 + tx * 4 + 3]) * g;
        *(float4*)&C[(size_t)row * N + c0 + tx * 4] = o;
    }
}

// ---------------------------------------------------------------------------
__global__ __launch_bounds__(256) void pad_ws1(const float* __restrict__ src,
                                               float* __restrict__ dst)
{
    const int r = blockIdx.x;
    for (int c = threadIdx.x; c < 2064; c += 256)
        dst[(size_t)r * 2064 + c] = (c < 2055) ? src[(size_t)r * 2055 + c] : 0.f;
}

// ---------------------------------------------------------------------------
__global__ __launch_bounds__(256) void gemm_si(
    const float* __restrict__ mu, const float* __restrict__ lam,
    const float* __restrict__ pi, const float* __restrict__ Wp,
    const float* __restrict__ bias, float* __restrict__ C)
{
    __shared__ float As[16][68];
    __shared__ float Ws[16][68];
    const int tid = threadIdx.x;
    const int tx = tid & 15, ty = tid >> 4;
    const int r0 = blockIdx.x * 64, c0 = blockIdx.y * 64;
    const int lr = tid >> 2;
    const int lk = (tid & 3) << 2;

    float acc[4][4] = {};

    for (int k0 = 0; k0 < 2064; k0 += 16) {
        const int kk = k0 + lk;
        float4 av;
        if (kk < 1024) {
            av = *(const float4*)&mu[(size_t)(r0 + lr) * 1024 + kk];
        } else if (kk < 2048) {
            float4 lv = *(const float4*)&lam[(size_t)(r0 + lr) * 1024 + (kk - 1024)];
            av.x = -logf(fmaxf(lv.x, 1e-6f));
            av.y = -logf(fmaxf(lv.y, 1e-6f));
            av.z = -logf(fmaxf(lv.z, 1e-6f));
            av.w = -logf(fmaxf(lv.w, 1e-6f));
        } else {
            #pragma unroll
            for (int i = 0; i < 4; ++i) {
                int k2 = kk + i - 2048;
                ((float*)&av)[i] = (k2 < 7) ? pi[(size_t)(r0 + lr) * 7 + k2] : 0.f;
            }
        }
        float4 wv = *(const float4*)&Wp[(size_t)(c0 + lr) * 2064 + kk];
        As[lk + 0][lr] = av.x; As[lk + 1][lr] = av.y;
        As[lk + 2][lr] = av.z; As[lk + 3][lr] = av.w;
        Ws[lk + 0][lr] = wv.x; Ws[lk + 1][lr] = wv.y;
        Ws[lk + 2][lr] = wv.z; Ws[lk + 3][lr] = wv.w;
        __syncthreads();
        #pragma unroll
        for (int kx = 0; kx < 16; ++kx) {
            float4 a = *(const float4*)&As[kx][ty * 4];
            float4 b = *(const float4*)&Ws[kx][tx * 4];
            acc[0][0] += a.x * b.x; acc[0][1] += a.x * b.y; acc[0][2] += a.x * b.z; acc[0][3] += a.x * b.w;
            acc[1][0] += a.y * b.x; acc[1][1] += a.y * b.y; acc[1][2] += a.y * b.z; acc[1][3] += a.y * b.w;
            acc[2][0] += a.z * b.x; acc[2][1] += a.z * b.y; acc[2][2] += a.z * b.z; acc[2][3] += a.z * b.w;
            acc[3][0] += a.w * b.x; acc[3][1] += a.w * b.y; acc[3][2] += a.w * b.z; acc[3][3] += a.w * b.w;
        }
        __syncthreads();
    }

    #pragma unroll
    for (int i = 0; i < 4; ++i) {
        int row = r0 + ty * 4 + i;
        float4 o;
        o.x = acc[i][0] + bias[c0 + tx * 4 + 0];
        o.y = acc[i][1] + bias[c0 + tx * 4 + 1];
        o.z = acc[i][2] + bias[c0 + tx * 4 + 2];
        o.w = acc[i][3] + bias[c0 + tx * 4 + 3];
        *(float4*)&C[(size_t)row * MMDIM + c0 + tx * 4] = o;
    }
}

// ---------------------------------------------------------------------------
__global__ __launch_bounds__(256) void s_kernel(
    const float* __restrict__ h, const float* __restrict__ Ws2,
    const float* __restrict__ bs2, float* __restrict__ sb,
    float* __restrict__ kap)
{
    const int tid = threadIdx.x;
    const int wave = tid >> 6, lane = tid & 63;
    const int t = blockIdx.x * 4 + wave;

    float4 hv = *(const float4*)&h[(size_t)t * MMDIM + lane * 4];
    float4 wv = *(const float4*)&Ws2[lane * 4];
    float p = 0.f;
    p += (hv.x / (1.f + expf(-hv.x))) * wv.x;
    p += (hv.y / (1.f + expf(-hv.y))) * wv.y;
    p += (hv.z / (1.f + expf(-hv.z))) * wv.z;
    p += (hv.w / (1.f + expf(-hv.w))) * wv.w;
    #pragma unroll
    for (int o = 32; o; o >>= 1) p += __shfl_xor(p, o);

    float z = p + bs2[0];
    float s = 1.f / (1.f + expf(-z));
    float c = s * 12.f;
    float Z = 0.f;
    #pragma unroll
    for (int l = 0; l < 13; ++l) {
        float d = (float)l - c;
        Z += expf(-0.5f * d * d);
    }
    Z = fmaxf(Z, 1e-8f);
    if (lane < 13) {
        float d = (float)lane - c;
        kap[(size_t)t * 16 + lane] = (1.f - s) * expf(-0.5f * d * d) / Z;
    }
    if (lane == 0) sb[t] = s;
}

// ---------------------------------------------------------------------------
__global__ __launch_bounds__(256) void scratch_kernel(
    const float* __restrict__ sq, const float* __restrict__ scr,
    const float* __restrict__ sb, float* __restrict__ ctx)
{
    const int tid = threadIdx.x;
    const int wave = tid >> 6, lane = tid & 63;
    const int t = blockIdx.x * 4 + wave;

    float4 qv = *(const float4*)&sq[(size_t)t * MMDIM + lane * 4];
    float4 fr[8];
    float sc[8];
    #pragma unroll
    for (int s = 0; s < 8; ++s) {
        fr[s] = *(const float4*)&scr[s * MMDIM + lane * 4];
        sc[s] = qv.x * fr[s].x + qv.y * fr[s].y + qv.z * fr[s].z + qv.w * fr[s].w;
    }
    #pragma unroll
    for (int s = 0; s < 8; ++s) {
        #pragma unroll
        for (int o = 32; o; o >>= 1) sc[s] += __shfl_xor(sc[s], o);
        sc[s] *= 0.0625f;
    }
    float mx = sc[0];
    #pragma unroll
    for (int s = 1; s < 8; ++s) mx = fmaxf(mx, sc[s]);
    float sum = 0.f;
    #pragma unroll
    for (int s = 0; s < 8; ++s) { sc[s] = expf(sc[s] - mx); sum += sc[s]; }
    float inv = 1.f / sum;
    float blend = sb[t];
    float4 o = {0, 0, 0, 0};
    #pragma unroll
    for (int s = 0; s < 8; ++s) {
        float pp = sc[s] * inv;
        o.x += pp * fr[s].x; o.y += pp * fr[s].y;
        o.z += pp * fr[s].z; o.w += pp * fr[s].w;
    }
    o.x *= blend; o.y *= blend; o.z *= blend; o.w *= blend;
    *(float4*)&ctx[(size_t)t * MMDIM + lane * 4] = o;
}

// ---------------------------------------------------------------------------
// w-tree: all levels of the weight tree, serial in LDS (tiny). Grid = BB.
// ---------------------------------------------------------------------------
__global__ __launch_bounds__(256) void wtree_kernel(
    const float* __restrict__ pw, float* __restrict__ wtree)
{
    __shared__ float wa[4096];
    __shared__ float wb2[2048];
    const int b = blockIdx.x;
    const int tid = threadIdx.x;
    for (int t = tid; t < 4096; t += 256) wa[t] = pw[b * 4096 + t];
    __syncthreads();
    int n = 4096, lvl = 1;
    float* cur = wa; float* nxt = wb2;
    while (n > 1) {
        int nout = n >> 1;
        int off = TT - (8192 >> lvl);
        for (int j = tid; j < nout; j += 256) {
            float t = cur[2 * j] + cur[2 * j + 1] + 1e-8f;
            nxt[j] = t;
            wtree[b * 4095 + off + j] = t;
        }
        __syncthreads();
        float* tmp = cur; cur = nxt; nxt = tmp;
        n = nout; ++lvl;
    }
}

// ---------------------------------------------------------------------------
// One tree level: out[j] = (w1*in[2j] + w2*in[2j+1]) / (w1+w2+1e-8).
// Block = one output node (k and v), grid (nout, BB).
// ---------------------------------------------------------------------------
__global__ __launch_bounds__(256) void tree_level(
    const float* __restrict__ kin, const float* __restrict__ vin,
    const float* __restrict__ win, float* __restrict__ kout,
    float* __restrict__ vout, int in_bs, int win_bs, int out_bs)
{
    const int j = blockIdx.x;
    const int b = blockIdx.y;
    const int tid = threadIdx.x;
    const float* wp = win + (size_t)b * win_bs;
    float w1 = wp[2 * j], w2 = wp[2 * j + 1];
    float tw = w1 + w2 + 1e-8f;
    size_t i1 = ((size_t)b * in_bs + 2 * j) * MMDIM + tid;
    size_t io = ((size_t)b * out_bs + j) * MMDIM + tid;
    kout[io] = (w1 * kin[i1] + w2 * kin[i1 + MMDIM]) / tw;
    vout[io] = (w1 * vin[i1] + w2 * vin[i1 + MMDIM]) / tw;
}

// ---------------------------------------------------------------------------
// f32 -> bf16 hi/lo split (RN both stages).
// ---------------------------------------------------------------------------
__device__ __forceinline__ unsigned short f2bf(float x)
{
    unsigned u = __float_as_uint(x);
    u += 0x7fffu + ((u >> 16) & 1u);
    return (unsigned short)(u >> 16);
}

__global__ __launch_bounds__(256) void convert_split(
    const float* __restrict__ src, unsigned short* __restrict__ hi,
    unsigned short* __restrict__ lo, int n4)
{
    int i = blockIdx.x * 256 + threadIdx.x;
    if (i >= n4) return;
    float4 x = ((const float4*)src)[i];
    ushort4 h, l;
    h.x = f2bf(x.x); l.x = f2bf(x.x - __uint_as_float((unsigned)h.x << 16));
    h.y = f2bf(x.y); l.y = f2bf(x.y - __uint_as_float((unsigned)h.y << 16));
    h.z = f2bf(x.z); l.z = f2bf(x.z - __uint_as_float((unsigned)h.z << 16));
    h.w = f2bf(x.w); l.w = f2bf(x.w - __uint_as_float((unsigned)h.w << 16));
    ((ushort4*)hi)[i] = h;
    ((ushort4*)lo)[i] = l;
}

// ---------------------------------------------------------------------------
// top-k helpers (tie-break: lower index, matching jax top_k)
// ---------------------------------------------------------------------------
__device__ __forceinline__ bool beats(float v, int id, float v2, int id2)
{
    return (v > v2) || (v == v2 && id < id2);
}

__device__ __forceinline__ void ins4(float v, int id, float tv[4], int ti[4])
{
    if (!beats(v, id, tv[3], ti[3])) return;
    tv[3] = v; ti[3] = id;
    #pragma unroll
    for (int s = 3; s > 0; --s) {
        if (beats(tv[s], ti[s], tv[s - 1], ti[s - 1])) {
            float fv = tv[s]; tv[s] = tv[s - 1]; tv[s - 1] = fv;
            int iv = ti[s]; ti[s] = ti[s - 1]; ti[s - 1] = iv;
        }
    }
}

__device__ __forceinline__ void ins5(float v, int id, float tv[5], int ti[5])
{
    if (!beats(v, id, tv[4], ti[4])) return;
    tv[4] = v; ti[4] = id;
    #pragma unroll
    for (int s = 4; s > 0; --s) {
        if (beats(tv[s], ti[s], tv[s - 1], ti[s - 1])) {
            float fv = tv[s]; tv[s] = tv[s - 1]; tv[s - 1] = fv;
            int iv = ti[s]; ti[s] = ti[s - 1]; ti[s - 1] = iv;
        }
    }
}

// slice id -> (level, col base). 39 slices of <=256 cols.
__device__ __forceinline__ void slice_map(int sid, int& level, int& c0)
{
    if (sid < 16)      { level = 0; c0 = sid << 8; }
    else if (sid < 24) { level = 1; c0 = (sid - 16) << 8; }
    else if (sid < 28) { level = 2; c0 = (sid - 24) << 8; }
    else if (sid < 30) { level = 3; c0 = (sid - 28) << 8; }
    else               { level = sid - 26; c0 = 0; }
}

// ---------------------------------------------------------------------------
// MFMA topk: approx scores via bf16 hi/lo 3-pass split (sigma ~2e-6), per-lane
// running top-4, butterfly to per-(row,slice) top-5 written to topw.
// Block: 256 thr = 4 waves x 16 rows (64 rows); 32-col LDS chunks.
// ---------------------------------------------------------------------------
__global__ __launch_bounds__(256) void topk_mfma(
    const unsigned short* __restrict__ qkh, const unsigned short* __restrict__ qkl,
    const unsigned short* __restrict__ kth, const unsigned short* __restrict__ ktl,
    float2* __restrict__ topw)
{
    __shared__ unsigned short kbh[32][264];
    __shared__ unsigned short kbl[32][264];

    const int tid = threadIdx.x;
    const int lane = tid & 63;
    const int wv = tid >> 6;
    const int r0 = blockIdx.x * 64;
    const int sid = blockIdx.y;
    const int b = r0 >> 12;
    const int t0 = r0 & 4095;

    int level, c0b;
    slice_map(sid, level, c0b);
    const int n = TT >> level;
    const int nv = min(min(n, t0 + 64), c0b + 256);

    if (c0b >= nv) {
        if (tid < 64) {
            float2 e = make_float2(-INFINITY, __int_as_float(0x7fffffff));
            #pragma unroll
            for (int s = 0; s < 5; ++s)
                topw[(size_t)(sid * 5 + s) * RTOT + r0 + tid] = e;
        }
        return;
    }

    const unsigned short* Kh;
    const unsigned short* Kl;
    if (level == 0) {
        Kh = qkh + (size_t)RTOT * MMDIM + (size_t)b * TT * MMDIM;
        Kl = qkl + (size_t)RTOT * MMDIM + (size_t)b * TT * MMDIM;
    } else {
        size_t off = (size_t)b * 4095 + (TT - (8192 >> level));
        Kh = kth + off * MMDIM;
        Kl = ktl + off * MMDIM;
    }

    // A fragments: row = l&15 within wave's 16-row group, k = (l>>4)*8 + i + 32*kt
    const int arow = r0 + wv * 16 + (lane & 15);
    const int koff = (lane >> 4) * 8;
    short8_t ah[8], al[8];
    #pragma unroll
    for (int kt = 0; kt < 8; ++kt) {
        ah[kt] = *(const short8_t*)(qkh + (size_t)arow * MMDIM + kt * 32 + koff);
        al[kt] = *(const short8_t*)(qkl + (size_t)arow * MMDIM + kt * 32 + koff);
    }

    float tv[4][4];
    int ti[4][4];
    #pragma unroll
    for (int r = 0; r < 4; ++r)
        #pragma unroll
        for (int s = 0; s < 4; ++s) { tv[r][s] = -INFINITY; ti[r][s] = 0x7fffffff; }

    const int scol = tid >> 3;
    const int kseg = (tid & 7) * 32;

    for (int c0 = c0b; c0 < nv; c0 += 32) {
        // stage 32 cols x 256 k of hi/lo bf16
        {
            int cc = min(c0 + scol, n - 1);
            const unsigned short* gh = Kh + (size_t)cc * MMDIM + kseg;
            const unsigned short* gl = Kl + (size_t)cc * MMDIM + kseg;
            #pragma unroll
            for (int i = 0; i < 4; ++i) {
                *(short8_t*)&kbh[scol][kseg + i * 8] = *(const short8_t*)(gh + i * 8);
                *(short8_t*)&kbl[scol][kseg + i * 8] = *(const short8_t*)(gl + i * 8);
            }
        }
        __syncthreads();

        #pragma unroll
        for (int ct = 0; ct < 2; ++ct) {
            f32x4 acc = {0.f, 0.f, 0.f, 0.f};
            const int bc = ct * 16 + (lane & 15);
            #pragma unroll
            for (int kt = 0; kt < 8; ++kt) {
                short8_t bh = *(const short8_t*)&kbh[bc][kt * 32 + koff];
                short8_t bl = *(const short8_t*)&kbl[bc][kt * 32 + koff];
                acc = __builtin_amdgcn_mfma_f32_16x16x32_bf16(ah[kt], bh, acc, 0, 0, 0);
                acc = __builtin_amdgcn_mfma_f32_16x16x32_bf16(al[kt], bh, acc, 0, 0, 0);
                acc = __builtin_amdgcn_mfma_f32_16x16x32_bf16(ah[kt], bl, acc, 0, 0, 0);
            }
            const int col = c0 + bc;
            #pragma unroll
            for (int r = 0; r < 4; ++r) {
                int trow = t0 + wv * 16 + (lane >> 4) * 4 + r;
                float cand = (col <= trow && col < n) ? acc[r] * 0.0625f : -INFINITY;
                if (__any(cand > tv[r][3])) ins4(cand, col, tv[r], ti[r]);
            }
        }
        __syncthreads();
    }

    // butterfly across 16 col-lanes -> top-5 per row, write
    #pragma unroll
    for (int r = 0; r < 4; ++r) {
        float v5[5]; int i5[5];
        #pragma unroll
        for (int s = 0; s < 4; ++s) { v5[s] = tv[r][s]; i5[s] = ti[r][s]; }
        v5[4] = -INFINITY; i5[4] = 0x7fffffff;
        #pragma unroll
        for (int pass = 0; pass < 4; ++pass) {
            int off = 1 << pass;
            float ov[5]; int oi[5];
            #pragma unroll
            for (int s = 0; s < 5; ++s) {
                ov[s] = __shfl_xor(v5[s], off);
                oi[s] = __shfl_xor(i5[s], off);
            }
            #pragma unroll
            for (int s = 0; s < 5; ++s) ins5(ov[s], oi[s], v5, i5);
        }
        if ((lane & 15) == 0) {
            int row = r0 + wv * 16 + (lane >> 4) * 4 + r;
            #pragma unroll
            for (int s = 0; s < 5; ++s)
                topw[(size_t)(sid * 5 + s) * RTOT + row] =
                    make_float2(v5[s], __int_as_float(i5[s]));
        }
    }
}

// ---------------------------------------------------------------------------
// Phase 2: merge slice top-5s per level; if the 4/5 gap is ambiguous (< 33
// sigma of the bf16-split error), exact-f32 rescore all candidates; softmax,
// kappa-weighted V gather; add to ctx (holds s*scratch_ctx). 1 wave per row.
// ---------------------------------------------------------------------------
__global__ __launch_bounds__(256) void merge_gather(
    const float2* __restrict__ topw, const float* __restrict__ q,
    const float* __restrict__ kl0, const float* __restrict__ ktf,
    const float* __restrict__ vl0, const float* __restrict__ vtree,
    const float* __restrict__ kap, float* __restrict__ ctx)
{
    const int tid = threadIdx.x;
    const int lane = tid & 63;
    const int wv = __builtin_amdgcn_readfirstlane(tid >> 6);
    const int row = blockIdx.x * 4 + wv;
    const int b = row >> 12;

    float cr[4] = {0, 0, 0, 0};
    const float4 q4 = *(const float4*)&q[(size_t)row * MMDIM + lane * 4];

    for (int l = 0; l <= 12; ++l) {
        int s0, cnt;
        if (l == 0)      { s0 = 0;  cnt = 16; }
        else if (l == 1) { s0 = 16; cnt = 8; }
        else if (l == 2) { s0 = 24; cnt = 4; }
        else if (l == 3) { s0 = 28; cnt = 2; }
        else             { s0 = 26 + l; cnt = 1; }

        float tv[5]; int ti[5];
        #pragma unroll
        for (int s = 0; s < 5; ++s) { tv[s] = -INFINITY; ti[s] = 0x7fffffff; }
        for (int sl = 0; sl < cnt; ++sl) {
            #pragma unroll
            for (int s = 0; s < 5; ++s) {
                float2 e = topw[(size_t)((s0 + sl) * 5 + s) * RTOT + row];
                if (e.x > -INFINITY) ins5(e.x, __float_as_int(e.y), tv, ti);
            }
        }

        const float* Kf = (l == 0)
            ? kl0 + (size_t)b * TT * MMDIM
            : ktf + ((size_t)b * 4095 + (TT - (8192 >> l))) * MMDIM;

        // ambiguity check: rescore exactly when approx gap(4,5) is tight
        bool ambig = (l <= 9) && (tv[3] - tv[4] < 1e-4f);
        if (ambig) {
            float rv[5]; int ri[5];
            #pragma unroll
            for (int s = 0; s < 5; ++s) { rv[s] = -INFINITY; ri[s] = 0x7fffffff; }
            for (int sl = 0; sl < cnt; ++sl) {
                #pragma unroll
                for (int s = 0; s < 5; ++s) {
                    float2 e = topw[(size_t)((s0 + sl) * 5 + s) * RTOT + row];
                    if (e.x > -INFINITY) {
                        int idx = __float_as_int(e.y);
                        float4 k4 = *(const float4*)&Kf[(size_t)idx * MMDIM + lane * 4];
                        float p = q4.x * k4.x + q4.y * k4.y + q4.z * k4.z + q4.w * k4.w;
                        #pragma unroll
                        for (int o = 32; o; o >>= 1) p += __shfl_xor(p, o);
                        ins5(p * 0.0625f, idx, rv, ri);
                    }
                }
            }
            #pragma unroll
            for (int s = 0; s < 5; ++s) { tv[s] = rv[s]; ti[s] = ri[s]; }
        }

        float m0 = tv[0];
        float e0 = expf(tv[0] - m0);
        float e1 = expf(tv[1] - m0);
        float e2 = expf(tv[2] - m0);
        float e3 = expf(tv[3] - m0);
        float sum = e0 + e1 + e2 + e3;
        float kp = kap[(size_t)row * 16 + l];
        float scl = kp / sum;
        float ps[4] = {e0 * scl, e1 * scl, e2 * scl, e3 * scl};

        const float* Vb = (l == 0)
            ? vl0 + (size_t)b * TT * MMDIM
            : vtree + ((size_t)b * 4095 + (TT - (8192 >> l))) * MMDIM;

        #pragma unroll
        for (int s = 0; s < 4; ++s) {
            if (ps[s] > 0.f) {
                float4 vv = *(const float4*)&Vb[(size_t)ti[s] * MMDIM + lane * 4];
                cr[0] += ps[s] * vv.x; cr[1] += ps[s] * vv.y;
                cr[2] += ps[s] * vv.z; cr[3] += ps[s] * vv.w;
            }
        }
    }

    float* cp = ctx + (size_t)row * MMDIM + lane * 4;
    float4 c = *(float4*)cp;
    c.x += cr[0]; c.y += cr[1]; c.z += cr[2]; c.w += cr[3];
    *(float4*)cp = c;
}

// ---------------------------------------------------------------------------
extern "C" void kernel_launch(void* const* d_in, const int* in_sizes, int n_in,
                              void* d_out, int out_size, void* d_ws, size_t ws_size,
                              hipStream_t stream)
{
    const float* mu  = (const float*)d_in[0];
    const float* lam = (const float*)d_in[1];
    const float* pi  = (const float*)d_in[2];
    const float* pw  = (const float*)d_in[3];
    const float* Wq  = (const float*)d_in[4];
    const float* bq  = (const float*)d_in[5];
    const float* Wk  = (const float*)d_in[6];
    const float* bk  = (const float*)d_in[7];
    const float* Wv  = (const float*)d_in[8];
    const float* bv  = (const float*)d_in[9];
    const float* Wo  = (const float*)d_in[10];
    const float* bo  = (const float*)d_in[11];
    const float* Ws1 = (const float*)d_in[12];
    const float* bs1 = (const float*)d_in[13];
    const float* Ws2 = (const float*)d_in[14];
    const float* bs2 = (const float*)d_in[15];
    const float* Wsr = (const float*)d_in[16];
    const float* bsr = (const float*)d_in[17];
    const float* scr = (const float*)d_in[18];
    const float* gate = (const float*)d_in[19];
    float* out = (float*)d_out;

    float* w = (float*)d_ws;
    const size_t RM = (size_t)RTOT * MMDIM;
    float* q_   = w;  w += RM;          // q_ and k_ must stay adjacent (joint convert)
    float* k_   = w;  w += RM;
    float* v_   = w;  w += RM;
    float* h_   = w;  w += RM;
    float* sq_  = w;  w += RM;
    float* ctx_ = w;  w += RM;
    float* sb_  = w;  w += RTOT;
    float* kap_ = w;  w += (size_t)RTOT * 16;
    float* kt_  = w;  w += (size_t)BB * 4095 * MMDIM;
    float* vt_  = w;  w += (size_t)BB * 4095 * MMDIM;
    float* w1p_ = w;  w += (size_t)256 * 2064;
    float* wtree_ = w; w += (size_t)BB * 4095;
    unsigned short* qkh_ = (unsigned short*)w;  w += RM;      // 2*RM ushorts
    unsigned short* qkl_ = (unsigned short*)w;  w += RM;
    unsigned short* kth_ = (unsigned short*)w;  w += (size_t)BB * 4095 * MMDIM / 2;
    unsigned short* ktl_ = (unsigned short*)w;  w += (size_t)BB * 4095 * MMDIM / 2;
    float2* topw = (float2*)w;  w += (size_t)NSLICE * 5 * RTOT * 2;

    gemm_f32<0><<<dim3(128, 4), 256, 0, stream>>>(mu, Wq, bq, nullptr, q_, 1024, 256);
    gemm_f32<0><<<dim3(128, 4), 256, 0, stream>>>(mu, Wk, bk, nullptr, k_, 1024, 256);
    gemm_f32<0><<<dim3(128, 4), 256, 0, stream>>>(mu, Wv, bv, nullptr, v_, 1024, 256);
    pad_ws1<<<256, 256, 0, stream>>>(Ws1, w1p_);
    gemm_si<<<dim3(128, 4), 256, 0, stream>>>(mu, lam, pi, w1p_, bs1, h_);
    s_kernel<<<2048, 256, 0, stream>>>(h_, Ws2, bs2, sb_, kap_);
    gemm_f32<0><<<dim3(128, 4), 256, 0, stream>>>(q_, Wsr, bsr, nullptr, sq_, 256, 256);
    scratch_kernel<<<2048, 256, 0, stream>>>(sq_, scr, sb_, ctx_);

    // weighted binary tree: w-tree then 12 wide per-level launches
    wtree_kernel<<<BB, 256, 0, stream>>>(pw, wtree_);
    {
        const float* kin = k_; const float* vin = v_; const float* win = pw;
        int in_bs = TT, win_bs = TT;
        for (int l = 1; l <= 12; ++l) {
            int nout = TT >> l;
            int off = TT - (8192 >> l);
            float* ko = kt_ + (size_t)off * MMDIM;
            float* vo = vt_ + (size_t)off * MMDIM;
            tree_level<<<dim3(nout, BB), 256, 0, stream>>>(kin, vin, win, ko, vo,
                                                           in_bs, win_bs, 4095);
            kin = ko; vin = vo; win = wtree_ + off;
            in_bs = 4095; win_bs = 4095;
        }
    }

    // bf16 hi/lo splits: q_+k_ jointly (adjacent), then the k-tree
    convert_split<<<(int)((2 * RM / 4 + 255) / 256), 256, 0, stream>>>(
        q_, qkh_, qkl_, (int)(2 * RM / 4));
    convert_split<<<(int)(((size_t)BB * 4095 * MMDIM / 4 + 255) / 256), 256, 0, stream>>>(
        kt_, kth_, ktl_, (int)((size_t)BB * 4095 * MMDIM / 4));

    topk_mfma<<<dim3(128, NSLICE), 256, 0, stream>>>(qkh_, qkl_, kth_, ktl_, topw);
    merge_gather<<<2048, 256, 0, stream>>>(topw, q_, k_, kt_, v_, vt_, kap_, ctx_);
    gemm_f32<1><<<dim3(128, 16), 256, 0, stream>>>(ctx_, Wo, bo, gate, out, 256, 1024);
}

// Round 5
// 873.190 us; speedup vs baseline: 4.8810x; 1.1004x over previous
//
#include <hip/hip_runtime.h>
#include <math.h>

#define TT 4096
#define BB 2
#define MMDIM 256
#define RTOT 8192
#define NSLICE 39

typedef __attribute__((ext_vector_type(8))) short short8_t;
typedef __attribute__((ext_vector_type(4))) float f32x4;

// ---------------------------------------------------------------------------
// f32 GEMM (kept for q,k: selection-critical, must stay f32-exact).
// ---------------------------------------------------------------------------
template<int WITH_GATE>
__global__ __launch_bounds__(256) void gemm_f32(
    const float* __restrict__ A, const float* __restrict__ W,
    const float* __restrict__ bias, const float* __restrict__ gate,
    float* __restrict__ C, int K, int N)
{
    __shared__ float As[16][68];
    __shared__ float Ws[16][68];
    const int tid = threadIdx.x;
    const int tx = tid & 15, ty = tid >> 4;
    const int r0 = blockIdx.x * 64, c0 = blockIdx.y * 64;
    const int lr = tid >> 2;
    const int lk = (tid & 3) << 2;

    float acc[4][4] = {};

    for (int k0 = 0; k0 < K; k0 += 16) {
        float4 av = *(const float4*)&A[(size_t)(r0 + lr) * K + k0 + lk];
        float4 wv = *(const float4*)&W[(size_t)(c0 + lr) * K + k0 + lk];
        As[lk + 0][lr] = av.x; As[lk + 1][lr] = av.y;
        As[lk + 2][lr] = av.z; As[lk + 3][lr] = av.w;
        Ws[lk + 0][lr] = wv.x; Ws[lk + 1][lr] = wv.y;
        Ws[lk + 2][lr] = wv.z; Ws[lk + 3][lr] = wv.w;
        __syncthreads();
        #pragma unroll
        for (int kk = 0; kk < 16; ++kk) {
            float4 a = *(const float4*)&As[kk][ty * 4];
            float4 b = *(const float4*)&Ws[kk][tx * 4];
            acc[0][0] += a.x * b.x; acc[0][1] += a.x * b.y; acc[0][2] += a.x * b.z; acc[0][3] += a.x * b.w;
            acc[1][0] += a.y * b.x; acc[1][1] += a.y * b.y; acc[1][2] += a.y * b.z; acc[1][3] += a.y * b.w;
            acc[2][0] += a.z * b.x; acc[2][1] += a.z * b.y; acc[2][2] += a.z * b.z; acc[2][3] += a.z * b.w;
            acc[3][0] += a.w * b.x; acc[3][1] += a.w * b.y; acc[3][2] += a.w * b.z; acc[3][3] += a.w * b.w;
        }
        __syncthreads();
    }

    float g = 1.f;
    if (WITH_GATE) g = 1.f / (1.f + expf(-gate[0]));
    #pragma unroll
    for (int i = 0; i < 4; ++i) {
        int row = r0 + ty * 4 + i;
        float4 o;
        o.x = (acc[i][0] + bias[c0 + tx * 4 + 0]) * g;
        o.y = (acc[i][1] + bias[c0 + tx * 4 + 1]) * g;
        o.z = (acc[i][2] + bias[c0 + tx * 4 + 2]) * g;
        o.w = (acc[i][3] + bias[c0 + tx * 4 + 3]) * g;
        *(float4*)&C[(size_t)row * N + c0 + tx * 4] = o;
    }
}

// ---------------------------------------------------------------------------
// f32 -> bf16 hi/lo split helpers (RNE both stages).
// ---------------------------------------------------------------------------
__device__ __forceinline__ unsigned short f2bf(float x)
{
    unsigned u = __float_as_uint(x);
    u += 0x7fffu + ((u >> 16) & 1u);
    return (unsigned short)(u >> 16);
}

__global__ __launch_bounds__(256) void convert_split(
    const float* __restrict__ src, unsigned short* __restrict__ hi,
    unsigned short* __restrict__ lo, int n4)
{
    int i = blockIdx.x * 256 + threadIdx.x;
    if (i >= n4) return;
    float4 x = ((const float4*)src)[i];
    ushort4 h, l;
    h.x = f2bf(x.x); l.x = f2bf(x.x - __uint_as_float((unsigned)h.x << 16));
    h.y = f2bf(x.y); l.y = f2bf(x.y - __uint_as_float((unsigned)h.y << 16));
    h.z = f2bf(x.z); l.z = f2bf(x.z - __uint_as_float((unsigned)h.z << 16));
    h.w = f2bf(x.w); l.w = f2bf(x.w - __uint_as_float((unsigned)h.w << 16));
    ((ushort4*)hi)[i] = h;
    ((ushort4*)lo)[i] = l;
}

// Ws1 [256][2055] -> split padded [256][2112]
__global__ __launch_bounds__(256) void pad_ws1_split(
    const float* __restrict__ src, unsigned short* __restrict__ hi,
    unsigned short* __restrict__ lo)
{
    const int r = blockIdx.x;
    for (int c = threadIdx.x; c < 2112; c += 256) {
        float v = (c < 2055) ? src[(size_t)r * 2055 + c] : 0.f;
        unsigned short h = f2bf(v);
        hi[(size_t)r * 2112 + c] = h;
        lo[(size_t)r * 2112 + c] = f2bf(v - __uint_as_float((unsigned)h << 16));
    }
}

// ---------------------------------------------------------------------------
// Split-bf16 3-pass MFMA GEMM: C[R][N] = A@W^T + bias (optional *sigmoid(gate)).
// A: f32, split inline during staging (ASRC=0) or generated si row (ASRC=1).
// W: pre-split hi/lo bf16 [N][K]. Tile 64 rows x 128 cols, KC=64, 4 waves.
// 16x16x32 bf16 MFMA, layout proven in topk (R4).
// ---------------------------------------------------------------------------
template<int ASRC, int WITH_GATE>
__global__ __launch_bounds__(256) void gemm_mfma(
    const float* __restrict__ A, const float* __restrict__ lam,
    const float* __restrict__ pi,
    const unsigned short* __restrict__ Wh, const unsigned short* __restrict__ Wl,
    const float* __restrict__ bias, const float* __restrict__ gate,
    float* __restrict__ C, int K, int N)
{
    __shared__ unsigned short Ah[64][72], Al[64][72];
    __shared__ unsigned short Bh[128][72], Bl[128][72];
    const int tid = threadIdx.x;
    const int lane = tid & 63;
    const int wv = tid >> 6;
    const int r0 = blockIdx.x * 64;
    const int c0 = blockIdx.y * 128;

    f32x4 acc0[8] = {}, acc1[8] = {}, acc2[8] = {};

    const int arow = wv * 16 + (lane & 15);
    const int koff = (lane >> 4) * 8;

    for (int kc = 0; kc < K; kc += 64) {
        // stage A with inline hi/lo split
        #pragma unroll
        for (int i = 0; i < 2; ++i) {
            int g = tid + i * 256;
            int row = g >> 3, gq = g & 7;
            float x[8];
            if (ASRC == 0) {
                float4 v0 = *(const float4*)&A[(size_t)(r0 + row) * K + kc + gq * 8];
                float4 v1 = *(const float4*)&A[(size_t)(r0 + row) * K + kc + gq * 8 + 4];
                x[0] = v0.x; x[1] = v0.y; x[2] = v0.z; x[3] = v0.w;
                x[4] = v1.x; x[5] = v1.y; x[6] = v1.z; x[7] = v1.w;
            } else {
                #pragma unroll
                for (int e = 0; e < 8; ++e) {
                    int c = kc + gq * 8 + e;
                    float val;
                    if (c < 1024)      val = A[(size_t)(r0 + row) * 1024 + c];
                    else if (c < 2048) val = -logf(fmaxf(lam[(size_t)(r0 + row) * 1024 + (c - 1024)], 1e-6f));
                    else if (c < 2055) val = pi[(size_t)(r0 + row) * 7 + (c - 2048)];
                    else               val = 0.f;
                    x[e] = val;
                }
            }
            short8_t sh, sl;
            #pragma unroll
            for (int e = 0; e < 8; ++e) {
                unsigned short h = f2bf(x[e]);
                sh[e] = (short)h;
                sl[e] = (short)f2bf(x[e] - __uint_as_float((unsigned)h << 16));
            }
            *(short8_t*)&Ah[row][gq * 8] = sh;
            *(short8_t*)&Al[row][gq * 8] = sl;
        }
        // stage W (pre-split, plain copy)
        #pragma unroll
        for (int i = 0; i < 4; ++i) {
            int g = tid + i * 256;
            int row = g >> 3, gq = g & 7;
            *(short8_t*)&Bh[row][gq * 8] = *(const short8_t*)&Wh[(size_t)(c0 + row) * K + kc + gq * 8];
            *(short8_t*)&Bl[row][gq * 8] = *(const short8_t*)&Wl[(size_t)(c0 + row) * K + kc + gq * 8];
        }
        __syncthreads();
        #pragma unroll
        for (int kt = 0; kt < 2; ++kt) {
            short8_t afh = *(const short8_t*)&Ah[arow][kt * 32 + koff];
            short8_t afl = *(const short8_t*)&Al[arow][kt * 32 + koff];
            #pragma unroll
            for (int ct = 0; ct < 8; ++ct) {
                short8_t bh = *(const short8_t*)&Bh[ct * 16 + (lane & 15)][kt * 32 + koff];
                short8_t bl = *(const short8_t*)&Bl[ct * 16 + (lane & 15)][kt * 32 + koff];
                acc0[ct] = __builtin_amdgcn_mfma_f32_16x16x32_bf16(afh, bh, acc0[ct], 0, 0, 0);
                acc1[ct] = __builtin_amdgcn_mfma_f32_16x16x32_bf16(afl, bh, acc1[ct], 0, 0, 0);
                acc2[ct] = __builtin_amdgcn_mfma_f32_16x16x32_bf16(afh, bl, acc2[ct], 0, 0, 0);
            }
        }
        __syncthreads();
    }

    float g = 1.f;
    if (WITH_GATE) g = 1.f / (1.f + expf(-gate[0]));
    #pragma unroll
    for (int ct = 0; ct < 8; ++ct) {
        int col = c0 + ct * 16 + (lane & 15);
        float b = bias[col];
        #pragma unroll
        for (int r = 0; r < 4; ++r) {
            int row = r0 + wv * 16 + (lane >> 4) * 4 + r;
            C[(size_t)row * N + col] = (acc0[ct][r] + acc1[ct][r] + acc2[ct][r] + b) * g;
        }
    }
}

// ---------------------------------------------------------------------------
__global__ __launch_bounds__(256) void s_kernel(
    const float* __restrict__ h, const float* __restrict__ Ws2,
    const float* __restrict__ bs2, float* __restrict__ sb,
    float* __restrict__ kap)
{
    const int tid = threadIdx.x;
    const int wave = tid >> 6, lane = tid & 63;
    const int t = blockIdx.x * 4 + wave;

    float4 hv = *(const float4*)&h[(size_t)t * MMDIM + lane * 4];
    float4 wv = *(const float4*)&Ws2[lane * 4];
    float p = 0.f;
    p += (hv.x / (1.f + expf(-hv.x))) * wv.x;
    p += (hv.y / (1.f + expf(-hv.y))) * wv.y;
    p += (hv.z / (1.f + expf(-hv.z))) * wv.z;
    p += (hv.w / (1.f + expf(-hv.w))) * wv.w;
    #pragma unroll
    for (int o = 32; o; o >>= 1) p += __shfl_xor(p, o);

    float z = p + bs2[0];
    float s = 1.f / (1.f + expf(-z));
    float c = s * 12.f;
    float Z = 0.f;
    #pragma unroll
    for (int l = 0; l < 13; ++l) {
        float d = (float)l - c;
        Z += expf(-0.5f * d * d);
    }
    Z = fmaxf(Z, 1e-8f);
    if (lane < 13) {
        float d = (float)lane - c;
        kap[(size_t)t * 16 + lane] = (1.f - s) * expf(-0.5f * d * d) / Z;
    }
    if (lane == 0) sb[t] = s;
}

// ---------------------------------------------------------------------------
__global__ __launch_bounds__(256) void scratch_kernel(
    const float* __restrict__ sq, const float* __restrict__ scr,
    const float* __restrict__ sb, float* __restrict__ ctx)
{
    const int tid = threadIdx.x;
    const int wave = tid >> 6, lane = tid & 63;
    const int t = blockIdx.x * 4 + wave;

    float4 qv = *(const float4*)&sq[(size_t)t * MMDIM + lane * 4];
    float4 fr[8];
    float sc[8];
    #pragma unroll
    for (int s = 0; s < 8; ++s) {
        fr[s] = *(const float4*)&scr[s * MMDIM + lane * 4];
        sc[s] = qv.x * fr[s].x + qv.y * fr[s].y + qv.z * fr[s].z + qv.w * fr[s].w;
    }
    #pragma unroll
    for (int s = 0; s < 8; ++s) {
        #pragma unroll
        for (int o = 32; o; o >>= 1) sc[s] += __shfl_xor(sc[s], o);
        sc[s] *= 0.0625f;
    }
    float mx = sc[0];
    #pragma unroll
    for (int s = 1; s < 8; ++s) mx = fmaxf(mx, sc[s]);
    float sum = 0.f;
    #pragma unroll
    for (int s = 0; s < 8; ++s) { sc[s] = expf(sc[s] - mx); sum += sc[s]; }
    float inv = 1.f / sum;
    float blend = sb[t];
    float4 o = {0, 0, 0, 0};
    #pragma unroll
    for (int s = 0; s < 8; ++s) {
        float pp = sc[s] * inv;
        o.x += pp * fr[s].x; o.y += pp * fr[s].y;
        o.z += pp * fr[s].z; o.w += pp * fr[s].w;
    }
    o.x *= blend; o.y *= blend; o.z *= blend; o.w *= blend;
    *(float4*)&ctx[(size_t)t * MMDIM + lane * 4] = o;
}

// ---------------------------------------------------------------------------
// w-tree: all levels of the weight tree, per batch.
// ---------------------------------------------------------------------------
__global__ __launch_bounds__(256) void wtree_kernel(
    const float* __restrict__ pw, float* __restrict__ wtree)
{
    __shared__ float wa[4096];
    __shared__ float wb2[2048];
    const int b = blockIdx.x;
    const int tid = threadIdx.x;
    for (int t = tid; t < 4096; t += 256) wa[t] = pw[b * 4096 + t];
    __syncthreads();
    int n = 4096, lvl = 1;
    float* cur = wa; float* nxt = wb2;
    while (n > 1) {
        int nout = n >> 1;
        int off = TT - (8192 >> lvl);
        for (int j = tid; j < nout; j += 256) {
            float t = cur[2 * j] + cur[2 * j + 1] + 1e-8f;
            nxt[j] = t;
            wtree[b * 4095 + off + j] = t;
        }
        __syncthreads();
        float* tmp = cur; cur = nxt; nxt = tmp;
        n = nout; ++lvl;
    }
}

// ---------------------------------------------------------------------------
// One tree level (used for l=1..6, wide grids).
// ---------------------------------------------------------------------------
__global__ __launch_bounds__(256) void tree_level(
    const float* __restrict__ kin, const float* __restrict__ vin,
    const float* __restrict__ win, float* __restrict__ kout,
    float* __restrict__ vout, int in_bs, int win_bs, int out_bs)
{
    const int j = blockIdx.x;
    const int b = blockIdx.y;
    const int tid = threadIdx.x;
    const float* wp = win + (size_t)b * win_bs;
    float w1 = wp[2 * j], w2 = wp[2 * j + 1];
    float tw = w1 + w2 + 1e-8f;
    size_t i1 = ((size_t)b * in_bs + 2 * j) * MMDIM + tid;
    size_t io = ((size_t)b * out_bs + j) * MMDIM + tid;
    kout[io] = (w1 * kin[i1] + w2 * kin[i1 + MMDIM]) / tw;
    vout[io] = (w1 * vin[i1] + w2 * vin[i1 + MMDIM]) / tw;
}

// ---------------------------------------------------------------------------
// Fused deep tree levels 7..12 (inputs: level-6 nodes in kt_/vt_; weights from
// wtree_). Block = (m-chunk, batch); all work in LDS.
// ---------------------------------------------------------------------------
__global__ __launch_bounds__(256) void tree_deep(
    float* __restrict__ kt_, float* __restrict__ vt_,
    const float* __restrict__ wtree)
{
    __shared__ float kb[128][68];
    __shared__ float vb[128][68];
    const int tid = threadIdx.x;
    const int mc = blockIdx.x;          // 0..3
    const int b = blockIdx.y;
    const int wb = b * 4095;

    // load level-6 (64 nodes x 64 m) into slots 0..63
    for (int idx = tid; idx < 64 * 64; idx += 256) {
        int j = idx >> 6, m = idx & 63;
        size_t gi = (size_t)(wb + 3968 + j) * MMDIM + mc * 64 + m;
        kb[j][m] = kt_[gi];
        vb[j][m] = vt_[gi];
    }
    __syncthreads();

    int pb = 0;
    for (int l = 7; l <= 12; ++l) {
        int nout = 4096 >> l;
        int cb = 128 - (128 >> (l - 6));
        int offm1 = TT - (8192 >> (l - 1));
        int offl  = TT - (8192 >> l);
        for (int idx = tid; idx < nout * 64; idx += 256) {
            int j = idx >> 6, m = idx & 63;
            float w1 = wtree[wb + offm1 + 2 * j];
            float w2 = wtree[wb + offm1 + 2 * j + 1];
            float tw = wtree[wb + offl + j];
            float kvv = (w1 * kb[pb + 2 * j][m] + w2 * kb[pb + 2 * j + 1][m]) / tw;
            float vvv = (w1 * vb[pb + 2 * j][m] + w2 * vb[pb + 2 * j + 1][m]) / tw;
            kb[cb + j][m] = kvv;
            vb[cb + j][m] = vvv;
            size_t go = (size_t)(wb + offl + j) * MMDIM + mc * 64 + m;
            kt_[go] = kvv;
            vt_[go] = vvv;
        }
        __syncthreads();
        pb = cb;
    }
}

// ---------------------------------------------------------------------------
// top-k helpers (tie-break: lower index, matching jax top_k)
// ---------------------------------------------------------------------------
__device__ __forceinline__ bool beats(float v, int id, float v2, int id2)
{
    return (v > v2) || (v == v2 && id < id2);
}

__device__ __forceinline__ void ins4(float v, int id, float tv[4], int ti[4])
{
    if (!beats(v, id, tv[3], ti[3])) return;
    tv[3] = v; ti[3] = id;
    #pragma unroll
    for (int s = 3; s > 0; --s) {
        if (beats(tv[s], ti[s], tv[s - 1], ti[s - 1])) {
            float fv = tv[s]; tv[s] = tv[s - 1]; tv[s - 1] = fv;
            int iv = ti[s]; ti[s] = ti[s - 1]; ti[s - 1] = iv;
        }
    }
}

__device__ __forceinline__ void ins5(float v, int id, float tv[5], int ti[5])
{
    if (!beats(v, id, tv[4], ti[4])) return;
    tv[4] = v; ti[4] = id;
    #pragma unroll
    for (int s = 4; s > 0; --s) {
        if (beats(tv[s], ti[s], tv[s - 1], ti[s - 1])) {
            float fv = tv[s]; tv[s] = tv[s - 1]; tv[s - 1] = fv;
            int iv = ti[s]; ti[s] = ti[s - 1]; ti[s - 1] = iv;
        }
    }
}

// slice id -> (level, col base). 39 slices of <=256 cols.
__device__ __forceinline__ void slice_map(int sid, int& level, int& c0)
{
    if (sid < 16)      { level = 0; c0 = sid << 8; }
    else if (sid < 24) { level = 1; c0 = (sid - 16) << 8; }
    else if (sid < 28) { level = 2; c0 = (sid - 24) << 8; }
    else if (sid < 30) { level = 3; c0 = (sid - 28) << 8; }
    else               { level = sid - 26; c0 = 0; }
}

// ---------------------------------------------------------------------------
// MFMA topk with 3 independent accumulator chains (pipeline fix vs R4).
// ---------------------------------------------------------------------------
__global__ __launch_bounds__(256) void topk_mfma(
    const unsigned short* __restrict__ qkh, const unsigned short* __restrict__ qkl,
    const unsigned short* __restrict__ kth, const unsigned short* __restrict__ ktl,
    float2* __restrict__ topw)
{
    __shared__ unsigned short kbh[32][264];
    __shared__ unsigned short kbl[32][264];

    const int tid = threadIdx.x;
    const int lane = tid & 63;
    const int wv = tid >> 6;
    const int r0 = blockIdx.x * 64;
    const int sid = blockIdx.y;
    const int b = r0 >> 12;
    const int t0 = r0 & 4095;

    int level, c0b;
    slice_map(sid, level, c0b);
    const int n = TT >> level;
    const int nv = min(min(n, t0 + 64), c0b + 256);

    if (c0b >= nv) {
        if (tid < 64) {
            float2 e = make_float2(-INFINITY, __int_as_float(0x7fffffff));
            #pragma unroll
            for (int s = 0; s < 5; ++s)
                topw[(size_t)(sid * 5 + s) * RTOT + r0 + tid] = e;
        }
        return;
    }

    const unsigned short* Kh;
    const unsigned short* Kl;
    if (level == 0) {
        Kh = qkh + (size_t)RTOT * MMDIM + (size_t)b * TT * MMDIM;
        Kl = qkl + (size_t)RTOT * MMDIM + (size_t)b * TT * MMDIM;
    } else {
        size_t off = (size_t)b * 4095 + (TT - (8192 >> level));
        Kh = kth + off * MMDIM;
        Kl = ktl + off * MMDIM;
    }

    const int arow = r0 + wv * 16 + (lane & 15);
    const int koff = (lane >> 4) * 8;
    short8_t ah[8], al[8];
    #pragma unroll
    for (int kt = 0; kt < 8; ++kt) {
        ah[kt] = *(const short8_t*)(qkh + (size_t)arow * MMDIM + kt * 32 + koff);
        al[kt] = *(const short8_t*)(qkl + (size_t)arow * MMDIM + kt * 32 + koff);
    }

    float tv[4][4];
    int ti[4][4];
    #pragma unroll
    for (int r = 0; r < 4; ++r)
        #pragma unroll
        for (int s = 0; s < 4; ++s) { tv[r][s] = -INFINITY; ti[r][s] = 0x7fffffff; }

    const int scol = tid >> 3;
    const int kseg = (tid & 7) * 32;

    for (int c0 = c0b; c0 < nv; c0 += 32) {
        {
            int cc = min(c0 + scol, n - 1);
            const unsigned short* gh = Kh + (size_t)cc * MMDIM + kseg;
            const unsigned short* gl = Kl + (size_t)cc * MMDIM + kseg;
            #pragma unroll
            for (int i = 0; i < 4; ++i) {
                *(short8_t*)&kbh[scol][kseg + i * 8] = *(const short8_t*)(gh + i * 8);
                *(short8_t*)&kbl[scol][kseg + i * 8] = *(const short8_t*)(gl + i * 8);
            }
        }
        __syncthreads();

        #pragma unroll
        for (int ct = 0; ct < 2; ++ct) {
            f32x4 a0 = {0.f, 0.f, 0.f, 0.f};
            f32x4 a1 = {0.f, 0.f, 0.f, 0.f};
            f32x4 a2 = {0.f, 0.f, 0.f, 0.f};
            const int bc = ct * 16 + (lane & 15);
            #pragma unroll
            for (int kt = 0; kt < 8; ++kt) {
                short8_t bh = *(const short8_t*)&kbh[bc][kt * 32 + koff];
                short8_t bl = *(const short8_t*)&kbl[bc][kt * 32 + koff];
                a0 = __builtin_amdgcn_mfma_f32_16x16x32_bf16(ah[kt], bh, a0, 0, 0, 0);
                a1 = __builtin_amdgcn_mfma_f32_16x16x32_bf16(al[kt], bh, a1, 0, 0, 0);
                a2 = __builtin_amdgcn_mfma_f32_16x16x32_bf16(ah[kt], bl, a2, 0, 0, 0);
            }
            const int col = c0 + bc;
            #pragma unroll
            for (int r = 0; r < 4; ++r) {
                int trow = t0 + wv * 16 + (lane >> 4) * 4 + r;
                float cand = (col <= trow && col < n)
                    ? (a0[r] + a1[r] + a2[r]) * 0.0625f : -INFINITY;
                if (__any(cand > tv[r][3])) ins4(cand, col, tv[r], ti[r]);
            }
        }
        __syncthreads();
    }

    #pragma unroll
    for (int r = 0; r < 4; ++r) {
        float v5[5]; int i5[5];
        #pragma unroll
        for (int s = 0; s < 4; ++s) { v5[s] = tv[r][s]; i5[s] = ti[r][s]; }
        v5[4] = -INFINITY; i5[4] = 0x7fffffff;
        #pragma unroll
        for (int pass = 0; pass < 4; ++pass) {
            int off = 1 << pass;
            float ov[5]; int oi[5];
            #pragma unroll
            for (int s = 0; s < 5; ++s) {
                ov[s] = __shfl_xor(v5[s], off);
                oi[s] = __shfl_xor(i5[s], off);
            }
            #pragma unroll
            for (int s = 0; s < 5; ++s) ins5(ov[s], oi[s], v5, i5);
        }
        if ((lane & 15) == 0) {
            int row = r0 + wv * 16 + (lane >> 4) * 4 + r;
            #pragma unroll
            for (int s = 0; s < 5; ++s)
                topw[(size_t)(sid * 5 + s) * RTOT + row] =
                    make_float2(v5[s], __int_as_float(i5[s]));
        }
    }
}

// ---------------------------------------------------------------------------
// Phase 2: merge slice top-5s per level; ambiguous rows get exact f32 rescore;
// softmax, kappa-weighted V gather; add to ctx. One wave per row.
// ---------------------------------------------------------------------------
__global__ __launch_bounds__(256) void merge_gather(
    const float2* __restrict__ topw, const float* __restrict__ q,
    const float* __restrict__ kl0, const float* __restrict__ ktf,
    const float* __restrict__ vl0, const float* __restrict__ vtree,
    const float* __restrict__ kap, float* __restrict__ ctx)
{
    const int tid = threadIdx.x;
    const int lane = tid & 63;
    const int wv = __builtin_amdgcn_readfirstlane(tid >> 6);
    const int row = blockIdx.x * 4 + wv;
    const int b = row >> 12;

    float cr[4] = {0, 0, 0, 0};
    const float4 q4 = *(const float4*)&q[(size_t)row * MMDIM + lane * 4];

    for (int l = 0; l <= 12; ++l) {
        int s0, cnt;
        if (l == 0)      { s0 = 0;  cnt = 16; }
        else if (l == 1) { s0 = 16; cnt = 8; }
        else if (l == 2) { s0 = 24; cnt = 4; }
        else if (l == 3) { s0 = 28; cnt = 2; }
        else             { s0 = 26 + l; cnt = 1; }

        float tv[5]; int ti[5];
        #pragma unroll
        for (int s = 0; s < 5; ++s) { tv[s] = -INFINITY; ti[s] = 0x7fffffff; }
        for (int sl = 0; sl < cnt; ++sl) {
            #pragma unroll
            for (int s = 0; s < 5; ++s) {
                float2 e = topw[(size_t)((s0 + sl) * 5 + s) * RTOT + row];
                if (e.x > -INFINITY) ins5(e.x, __float_as_int(e.y), tv, ti);
            }
        }

        const float* Kf = (l == 0)
            ? kl0 + (size_t)b * TT * MMDIM
            : ktf + ((size_t)b * 4095 + (TT - (8192 >> l))) * MMDIM;

        bool ambig = (l <= 9) && (tv[3] - tv[4] < 1e-4f);
        if (ambig) {
            float rv[5]; int ri[5];
            #pragma unroll
            for (int s = 0; s < 5; ++s) { rv[s] = -INFINITY; ri[s] = 0x7fffffff; }
            for (int sl = 0; sl < cnt; ++sl) {
                #pragma unroll
                for (int s = 0; s < 5; ++s) {
                    float2 e = topw[(size_t)((s0 + sl) * 5 + s) * RTOT + row];
                    if (e.x > -INFINITY) {
                        int idx = __float_as_int(e.y);
                        float4 k4 = *(const float4*)&Kf[(size_t)idx * MMDIM + lane * 4];
                        float p = q4.x * k4.x + q4.y * k4.y + q4.z * k4.z + q4.w * k4.w;
                        #pragma unroll
                        for (int o = 32; o; o >>= 1) p += __shfl_xor(p, o);
                        ins5(p * 0.0625f, idx, rv, ri);
                    }
                }
            }
            #pragma unroll
            for (int s = 0; s < 5; ++s) { tv[s] = rv[s]; ti[s] = ri[s]; }
        }

        float m0 = tv[0];
        float e0 = expf(tv[0] - m0);
        float e1 = expf(tv[1] - m0);
        float e2 = expf(tv[2] - m0);
        float e3 = expf(tv[3] - m0);
        float sum = e0 + e1 + e2 + e3;
        float kp = kap[(size_t)row * 16 + l];
        float scl = kp / sum;
        float ps[4] = {e0 * scl, e1 * scl, e2 * scl, e3 * scl};

        const float* Vb = (l == 0)
            ? vl0 + (size_t)b * TT * MMDIM
            : vtree + ((size_t)b * 4095 + (TT - (8192 >> l))) * MMDIM;

        #pragma unroll
        for (int s = 0; s < 4; ++s) {
            if (ps[s] > 0.f) {
                float4 vv = *(const float4*)&Vb[(size_t)ti[s] * MMDIM + lane * 4];
                cr[0] += ps[s] * vv.x; cr[1] += ps[s] * vv.y;
                cr[2] += ps[s] * vv.z; cr[3] += ps[s] * vv.w;
            }
        }
    }

    float* cp = ctx + (size_t)row * MMDIM + lane * 4;
    float4 c = *(float4*)cp;
    c.x += cr[0]; c.y += cr[1]; c.z += cr[2]; c.w += cr[3];
    *(float4*)cp = c;
}

// ---------------------------------------------------------------------------
extern "C" void kernel_launch(void* const* d_in, const int* in_sizes, int n_in,
                              void* d_out, int out_size, void* d_ws, size_t ws_size,
                              hipStream_t stream)
{
    const float* mu  = (const float*)d_in[0];
    const float* lam = (const float*)d_in[1];
    const float* pi  = (const float*)d_in[2];
    const float* pw  = (const float*)d_in[3];
    const float* Wq  = (const float*)d_in[4];
    const float* bq  = (const float*)d_in[5];
    const float* Wk  = (const float*)d_in[6];
    const float* bk  = (const float*)d_in[7];
    const float* Wv  = (const float*)d_in[8];
    const float* bv  = (const float*)d_in[9];
    const float* Wo  = (const float*)d_in[10];
    const float* bo  = (const float*)d_in[11];
    const float* Ws1 = (const float*)d_in[12];
    const float* bs1 = (const float*)d_in[13];
    const float* Ws2 = (const float*)d_in[14];
    const float* bs2 = (const float*)d_in[15];
    const float* Wsr = (const float*)d_in[16];
    const float* bsr = (const float*)d_in[17];
    const float* scr = (const float*)d_in[18];
    const float* gate = (const float*)d_in[19];
    float* out = (float*)d_out;

    float* w = (float*)d_ws;
    const size_t RM = (size_t)RTOT * MMDIM;
    float* q_   = w;  w += RM;          // q_,k_ adjacent (joint convert for topk)
    float* k_   = w;  w += RM;
    float* v_   = w;  w += RM;
    float* h_   = w;  w += RM;
    float* sq_  = w;  w += RM;
    float* ctx_ = w;  w += RM;
    float* sb_  = w;  w += RTOT;
    float* kap_ = w;  w += (size_t)RTOT * 16;
    float* kt_  = w;  w += (size_t)BB * 4095 * MMDIM;
    float* vt_  = w;  w += (size_t)BB * 4095 * MMDIM;
    float* wtree_ = w; w += (size_t)BB * 4095;
    unsigned short* qkh_ = (unsigned short*)w;  w += RM;      // 2*RM ushorts
    unsigned short* qkl_ = (unsigned short*)w;  w += RM;
    unsigned short* kth_ = (unsigned short*)w;  w += (size_t)BB * 4095 * MMDIM / 2;
    unsigned short* ktl_ = (unsigned short*)w;  w += (size_t)BB * 4095 * MMDIM / 2;
    float2* topw = (float2*)w;  w += (size_t)NSLICE * 5 * RTOT * 2;
    unsigned short* w1h_ = (unsigned short*)w;  w += (size_t)256 * 2112 / 2;
    unsigned short* w1l_ = (unsigned short*)w;  w += (size_t)256 * 2112 / 2;
    unsigned short* wvh_ = (unsigned short*)w;  w += (size_t)256 * 1024 / 2;
    unsigned short* wvl_ = (unsigned short*)w;  w += (size_t)256 * 1024 / 2;
    unsigned short* wsrh_ = (unsigned short*)w; w += (size_t)256 * 256 / 2;
    unsigned short* wsrl_ = (unsigned short*)w; w += (size_t)256 * 256 / 2;
    unsigned short* woh_ = (unsigned short*)w;  w += (size_t)1024 * 256 / 2;
    unsigned short* wol_ = (unsigned short*)w;  w += (size_t)1024 * 256 / 2;

    // weight splits
    pad_ws1_split<<<256, 256, 0, stream>>>(Ws1, w1h_, w1l_);
    convert_split<<<256, 256, 0, stream>>>(Wv, wvh_, wvl_, 65536);
    convert_split<<<64, 256, 0, stream>>>(Wsr, wsrh_, wsrl_, 16384);
    convert_split<<<256, 256, 0, stream>>>(Wo, woh_, wol_, 65536);

    // projections: q,k exact f32 (selection-critical); v,h via split MFMA
    gemm_f32<0><<<dim3(128, 4), 256, 0, stream>>>(mu, Wq, bq, nullptr, q_, 1024, 256);
    gemm_f32<0><<<dim3(128, 4), 256, 0, stream>>>(mu, Wk, bk, nullptr, k_, 1024, 256);
    gemm_mfma<0, 0><<<dim3(128, 2), 256, 0, stream>>>(mu, nullptr, nullptr, wvh_, wvl_,
                                                      bv, nullptr, v_, 1024, 256);
    gemm_mfma<1, 0><<<dim3(128, 2), 256, 0, stream>>>(mu, lam, pi, w1h_, w1l_,
                                                      bs1, nullptr, h_, 2112, 256);
    s_kernel<<<2048, 256, 0, stream>>>(h_, Ws2, bs2, sb_, kap_);
    gemm_mfma<0, 0><<<dim3(128, 2), 256, 0, stream>>>(q_, nullptr, nullptr, wsrh_, wsrl_,
                                                      bsr, nullptr, sq_, 256, 256);
    scratch_kernel<<<2048, 256, 0, stream>>>(sq_, scr, sb_, ctx_);

    // weighted binary tree: w-tree, wide levels 1..6, fused deep levels 7..12
    wtree_kernel<<<BB, 256, 0, stream>>>(pw, wtree_);
    {
        const float* kin = k_; const float* vin = v_; const float* win = pw;
        int in_bs = TT, win_bs = TT;
        for (int l = 1; l <= 6; ++l) {
            int nout = TT >> l;
            int off = TT - (8192 >> l);
            float* ko = kt_ + (size_t)off * MMDIM;
            float* vo = vt_ + (size_t)off * MMDIM;
            tree_level<<<dim3(nout, BB), 256, 0, stream>>>(kin, vin, win, ko, vo,
                                                           in_bs, win_bs, 4095);
            kin = ko; vin = vo; win = wtree_ + off;
            in_bs = 4095; win_bs = 4095;
        }
    }
    tree_deep<<<dim3(4, BB), 256, 0, stream>>>(kt_, vt_, wtree_);

    // bf16 hi/lo splits for the score path
    convert_split<<<(int)((2 * RM / 4 + 255) / 256), 256, 0, stream>>>(
        q_, qkh_, qkl_, (int)(2 * RM / 4));
    convert_split<<<(int)(((size_t)BB * 4095 * MMDIM / 4 + 255) / 256), 256, 0, stream>>>(
        kt_, kth_, ktl_, (int)((size_t)BB * 4095 * MMDIM / 4));

    topk_mfma<<<dim3(128, NSLICE), 256, 0, stream>>>(qkh_, qkl_, kth_, ktl_, topw);
    merge_gather<<<2048, 256, 0, stream>>>(topw, q_, k_, kt_, v_, vt_, kap_, ctx_);
    gemm_mfma<0, 1><<<dim3(128, 8), 256, 0, stream>>>(ctx_, nullptr, nullptr, woh_, wol_,
                                                      bo, gate, out, 256, 1024);
}